// Round 1
// baseline (957.087 us; speedup 1.0000x reference)
//
#include <hip/hip_runtime.h>
#include <cstdint>
#include <math.h>

constexpr int PB = 8;
constexpr int NS = 1024;
constexpr int DM = 768;
constexpr int NH = 12;
constexpr int HSZ = 64;
constexpr float SCL = 8.0f;   // reference MULTIPLIES by sqrt(head_size)

// ---------------- GEMM: C = A(MxK) @ B(KxNB) + bias ----------------
// BM=128, BN=128, BK=16, 256 threads, 8x8 microtile (split 4+4 rows/cols).
// MODE 0: row-major store (ldc = NB).  MODE 1: scatter into (3,P,H,N,HS).
template <int MODE>
__global__ __launch_bounds__(256, 2)
void gemm_kernel(const float* __restrict__ A, const float* __restrict__ B,
                 const float* __restrict__ bias, float* __restrict__ Cout,
                 int M, int K, int NB)
{
    __shared__ float As[16][132];   // A^T tile: [k][m], pitch 132 keeps 16B align
    __shared__ float Bs[16][132];   // B tile:   [k][n]
    const int t  = threadIdx.x;
    const int m0 = blockIdx.y * 128;
    const int n0 = blockIdx.x * 128;
    const int tm = t >> 4;
    const int tn = t & 15;

    float acc[8][8];
    #pragma unroll
    for (int i = 0; i < 8; ++i)
        #pragma unroll
        for (int j = 0; j < 8; ++j) acc[i][j] = 0.f;

    const int arow = t >> 2;   // 0..63
    const int aseg = t & 3;    // 0..3
    const int brow = t >> 5;   // 0..7
    const int bseg = t & 31;   // 0..31

    for (int k0 = 0; k0 < K; k0 += 16) {
        #pragma unroll
        for (int r = 0; r < 2; ++r) {
            const int row = arow + r * 64;
            const float4 av = *(const float4*)(A + (size_t)(m0 + row) * K + k0 + aseg * 4);
            As[aseg*4+0][row] = av.x;
            As[aseg*4+1][row] = av.y;
            As[aseg*4+2][row] = av.z;
            As[aseg*4+3][row] = av.w;
        }
        #pragma unroll
        for (int r = 0; r < 2; ++r) {
            const int row = brow + r * 8;
            *(float4*)&Bs[row][bseg*4] =
                *(const float4*)(B + (size_t)(k0 + row) * NB + n0 + bseg * 4);
        }
        __syncthreads();
        #pragma unroll
        for (int kk = 0; kk < 16; ++kk) {
            float ar[8], br[8];
            *(float4*)&ar[0] = *(const float4*)&As[kk][tm*4];
            *(float4*)&ar[4] = *(const float4*)&As[kk][64 + tm*4];
            *(float4*)&br[0] = *(const float4*)&Bs[kk][tn*4];
            *(float4*)&br[4] = *(const float4*)&Bs[kk][64 + tn*4];
            #pragma unroll
            for (int i = 0; i < 8; ++i)
                #pragma unroll
                for (int j = 0; j < 8; ++j)
                    acc[i][j] = fmaf(ar[i], br[j], acc[i][j]);
        }
        __syncthreads();
    }

    if (MODE == 0) {
        #pragma unroll
        for (int half = 0; half < 2; ++half) {
            const int col = n0 + half*64 + tn*4;
            const float4 bv = *(const float4*)&bias[col];
            #pragma unroll
            for (int i = 0; i < 8; ++i) {
                const int row = m0 + ((i < 4) ? (tm*4 + i) : (64 + tm*4 + i - 4));
                float4 o;
                o.x = acc[i][half*4+0] + bv.x;
                o.y = acc[i][half*4+1] + bv.y;
                o.z = acc[i][half*4+2] + bv.z;
                o.w = acc[i][half*4+3] + bv.w;
                *(float4*)(Cout + (size_t)row * NB + col) = o;
            }
        }
    } else {
        // columns j = c*768 + h*64 + s ; each 64-col half is one (c,h)
        #pragma unroll
        for (int half = 0; half < 2; ++half) {
            const int jbase = n0 + half*64;
            const int c  = jbase / DM;
            const int hh = (jbase % DM) >> 6;
            const int s0 = tn * 4;
            const float4 bv = *(const float4*)&bias[jbase + s0];
            #pragma unroll
            for (int i = 0; i < 8; ++i) {
                const int row = m0 + ((i < 4) ? (tm*4 + i) : (64 + tm*4 + i - 4));
                const int pp = row >> 10;
                const int nn = row & 1023;
                float4 o;
                o.x = acc[i][half*4+0] + bv.x;
                o.y = acc[i][half*4+1] + bv.y;
                o.z = acc[i][half*4+2] + bv.z;
                o.w = acc[i][half*4+3] + bv.w;
                const size_t idx = ((((size_t)(c*PB + pp) * NH + hh) * NS + nn) << 6) + s0;
                *(float4*)(Cout + idx) = o;
            }
        }
    }
}

// ---------------- Flash-style attention ----------------
// Block: (q-tile of 64 rows, h, p). 256 threads, 4x4 microtiles.
// Online softmax state (m,l,alpha) in registers via width-16 shfl reductions.
// Post-softmax mask-add handled exactly: ctx = O/l + (mask_row @ V).
__global__ __launch_bounds__(256, 2)
void attn_kernel(const float* __restrict__ qkv, const float* __restrict__ mask,
                 float* __restrict__ ctx)
{
    __shared__ float qs[64][68];   // Q^T: [s][q-row]
    __shared__ float ks[64][68];   // K^T: [s][k-col]; reused as P row-major [q-row][k]
    __shared__ float vs[64][68];   // V:   [k][c]
    __shared__ float ms_s[64];     // mask tile

    const int t  = threadIdx.x;
    const int qt = blockIdx.x;
    const int h  = blockIdx.y;
    const int pz = blockIdx.z;
    const int tq = t >> 4;
    const int tn = t & 15;

    const float* qb = qkv + (((size_t)(0*PB + pz) * NH + h) * NS + qt * 64) * HSZ;
    const float* kb = qkv + (((size_t)(1*PB + pz) * NH + h) * NS) * HSZ;
    const float* vb = qkv + (((size_t)(2*PB + pz) * NH + h) * NS) * HSZ;
    const float* mb = mask + (size_t)pz * NS;

    // load Q transposed into qs[s][row]
    #pragma unroll
    for (int r = 0; r < 4; ++r) {
        const int f = t + 256 * r;
        const int row = f >> 4, seg = f & 15;
        const float4 v = *(const float4*)(qb + row * 64 + seg * 4);
        qs[seg*4+0][row] = v.x;
        qs[seg*4+1][row] = v.y;
        qs[seg*4+2][row] = v.z;
        qs[seg*4+3][row] = v.w;
    }

    float o[4][4] = {{0.f}};
    float mv[4] = {0.f, 0.f, 0.f, 0.f};
    float m_run[4], l_run[4];
    #pragma unroll
    for (int i = 0; i < 4; ++i) { m_run[i] = -INFINITY; l_run[i] = 0.f; }

    for (int kt = 0; kt < 16; ++kt) {
        __syncthreads();   // previous tile's PV reads of ks(P)/vs complete
        #pragma unroll
        for (int r = 0; r < 4; ++r) {
            const int f = t + 256 * r;
            const int row = f >> 4, seg = f & 15;
            const float4 kv4 = *(const float4*)(kb + (size_t)(kt*64 + row) * 64 + seg * 4);
            ks[seg*4+0][row] = kv4.x;
            ks[seg*4+1][row] = kv4.y;
            ks[seg*4+2][row] = kv4.z;
            ks[seg*4+3][row] = kv4.w;
            *(float4*)&vs[row][seg*4] =
                *(const float4*)(vb + (size_t)(kt*64 + row) * 64 + seg * 4);
        }
        if (t < 64) ms_s[t] = mb[kt*64 + t];
        __syncthreads();

        // S = Q K^T (4x4 microtile): rows tq*4+i, k-cols tn*4+j
        float sa[4][4] = {{0.f}};
        #pragma unroll 8
        for (int s = 0; s < 64; ++s) {
            const float4 a4 = *(const float4*)&qs[s][tq*4];
            const float4 b4 = *(const float4*)&ks[s][tn*4];
            const float av[4] = {a4.x, a4.y, a4.z, a4.w};
            const float bv[4] = {b4.x, b4.y, b4.z, b4.w};
            #pragma unroll
            for (int i = 0; i < 4; ++i)
                #pragma unroll
                for (int j = 0; j < 4; ++j)
                    sa[i][j] = fmaf(av[i], bv[j], sa[i][j]);
        }

        // online softmax in registers (rows span 16 contiguous lanes)
        float alpha[4], p[4][4];
        #pragma unroll
        for (int i = 0; i < 4; ++i) {
            float lm = -INFINITY;
            #pragma unroll
            for (int j = 0; j < 4; ++j) { sa[i][j] *= SCL; lm = fmaxf(lm, sa[i][j]); }
            #pragma unroll
            for (int off = 1; off < 16; off <<= 1) lm = fmaxf(lm, __shfl_xor(lm, off, 16));
            const float m_new = fmaxf(m_run[i], lm);
            alpha[i] = __expf(m_run[i] - m_new);
            m_run[i] = m_new;
            float ls = 0.f;
            #pragma unroll
            for (int j = 0; j < 4; ++j) { p[i][j] = __expf(sa[i][j] - m_new); ls += p[i][j]; }
            #pragma unroll
            for (int off = 1; off < 16; off <<= 1) ls += __shfl_xor(ls, off, 16);
            l_run[i] = l_run[i] * alpha[i] + ls;
        }

        __syncthreads();   // all S-reads of ks done; safe to overwrite with P
        #pragma unroll
        for (int i = 0; i < 4; ++i) {
            *(float4*)&ks[tq*4+i][tn*4] = make_float4(p[i][0], p[i][1], p[i][2], p[i][3]);
            #pragma unroll
            for (int j = 0; j < 4; ++j) o[i][j] *= alpha[i];
        }
        __syncthreads();   // P visible

        // O += P @ V ; mv += mask @ V   (P row-major chunks of 4 k)
        #pragma unroll 4
        for (int k4 = 0; k4 < 16; ++k4) {
            float prr[4][4], vvv[4][4];
            #pragma unroll
            for (int i = 0; i < 4; ++i) {
                const float4 pr = *(const float4*)&ks[tq*4+i][k4*4];
                prr[i][0] = pr.x; prr[i][1] = pr.y; prr[i][2] = pr.z; prr[i][3] = pr.w;
            }
            #pragma unroll
            for (int u = 0; u < 4; ++u) {
                const float4 vv = *(const float4*)&vs[k4*4+u][tn*4];
                vvv[u][0] = vv.x; vvv[u][1] = vv.y; vvv[u][2] = vv.z; vvv[u][3] = vv.w;
            }
            #pragma unroll
            for (int u = 0; u < 4; ++u) {
                const float mk = ms_s[k4*4 + u];
                #pragma unroll
                for (int j = 0; j < 4; ++j) {
                    #pragma unroll
                    for (int i = 0; i < 4; ++i)
                        o[i][j] = fmaf(prr[i][u], vvv[u][j], o[i][j]);
                    mv[j] = fmaf(mk, vvv[u][j], mv[j]);
                }
            }
        }
    }

    // epilogue: ctx[p, n, h*64 + c] = O/l + mask@V
    #pragma unroll
    for (int i = 0; i < 4; ++i) {
        const int r = tq*4 + i;
        const float inv = 1.0f / l_run[i];
        float4 o4;
        o4.x = o[i][0]*inv + mv[0];
        o4.y = o[i][1]*inv + mv[1];
        o4.z = o[i][2]*inv + mv[2];
        o4.w = o[i][3]*inv + mv[3];
        *(float4*)(ctx + ((size_t)pz * NS + qt*64 + r) * DM + h*64 + tn*4) = o4;
    }
}

extern "C" void kernel_launch(void* const* d_in, const int* in_sizes, int n_in,
                              void* d_out, int out_size, void* d_ws, size_t ws_size,
                              hipStream_t stream)
{
    const float* x      = (const float*)d_in[0];
    const float* mask   = (const float*)d_in[1];
    const float* qkv_w  = (const float*)d_in[2];
    const float* qkv_b  = (const float*)d_in[3];
    const float* proj_w = (const float*)d_in[4];
    const float* proj_b = (const float*)d_in[5];
    float* out = (float*)d_out;

    // workspace: qkv (3,P,H,N,HS) = 75.5 MB ; ctx (P,N,D) = 25.2 MB
    float* qkv = (float*)d_ws;
    float* ctx = qkv + (size_t)3 * PB * NH * NS * HSZ;

    gemm_kernel<1><<<dim3(3*DM/128, PB*NS/128), 256, 0, stream>>>(
        x, qkv_w, qkv_b, qkv, PB*NS, DM, 3*DM);
    attn_kernel<<<dim3(NS/64, NH, PB), 256, 0, stream>>>(qkv, mask, ctx);
    gemm_kernel<0><<<dim3(DM/128, PB*NS/128), 256, 0, stream>>>(
        ctx, proj_w, proj_b, out, PB*NS, DM, DM);
}

// Round 2
// 854.831 us; speedup vs baseline: 1.1196x; 1.1196x over previous
//
#include <hip/hip_runtime.h>
#include <hip/hip_bf16.h>
#include <cstdint>
#include <math.h>

constexpr int PB = 8;
constexpr int NS = 1024;
constexpr int DM = 768;
constexpr int NH = 12;
constexpr int HSZ = 64;
constexpr float SCL = 8.0f;   // reference MULTIPLIES by sqrt(head_size)

typedef short bf16x8 __attribute__((ext_vector_type(8)));
typedef float floatx4 __attribute__((ext_vector_type(4)));

__device__ __forceinline__ ushort f2bf(float x) {
    __hip_bfloat16 b = __float2bfloat16(x);
    return *reinterpret_cast<ushort*>(&b);
}
__device__ __forceinline__ float bf2f(ushort u) {
    __hip_bfloat16 b = *reinterpret_cast<__hip_bfloat16*>(&u);
    return __bfloat162float(b);
}

// ---------------- GEMM: C = A(MxK) @ B(KxNB) + bias ----------------
// BM=128, BN=128, BK=16, 256 threads, 8x8 microtile.
// MODE 0: row-major fp32 store (ldc = NB).
// MODE 1: split-bf16 scatter: q_hi/q_lo/k_hi/k_lo (P,H,N,64), vT (P,H,64,N).
template <int MODE>
__global__ __launch_bounds__(256, 2)
void gemm_kernel(const float* __restrict__ A, const float* __restrict__ B,
                 const float* __restrict__ bias, float* __restrict__ Cout,
                 ushort* __restrict__ qhp, ushort* __restrict__ qlp,
                 ushort* __restrict__ khp, ushort* __restrict__ klp,
                 ushort* __restrict__ vtp,
                 int M, int K, int NB)
{
    __shared__ float As[16][132];
    __shared__ float Bs[16][132];
    const int t  = threadIdx.x;
    const int m0 = blockIdx.y * 128;
    const int n0 = blockIdx.x * 128;
    const int tm = t >> 4;
    const int tn = t & 15;

    float acc[8][8];
    #pragma unroll
    for (int i = 0; i < 8; ++i)
        #pragma unroll
        for (int j = 0; j < 8; ++j) acc[i][j] = 0.f;

    const int arow = t >> 2;
    const int aseg = t & 3;
    const int brow = t >> 5;
    const int bseg = t & 31;

    for (int k0 = 0; k0 < K; k0 += 16) {
        #pragma unroll
        for (int r = 0; r < 2; ++r) {
            const int row = arow + r * 64;
            const float4 av = *(const float4*)(A + (size_t)(m0 + row) * K + k0 + aseg * 4);
            As[aseg*4+0][row] = av.x;
            As[aseg*4+1][row] = av.y;
            As[aseg*4+2][row] = av.z;
            As[aseg*4+3][row] = av.w;
        }
        #pragma unroll
        for (int r = 0; r < 2; ++r) {
            const int row = brow + r * 8;
            *(float4*)&Bs[row][bseg*4] =
                *(const float4*)(B + (size_t)(k0 + row) * NB + n0 + bseg * 4);
        }
        __syncthreads();
        #pragma unroll
        for (int kk = 0; kk < 16; ++kk) {
            float ar[8], br[8];
            *(float4*)&ar[0] = *(const float4*)&As[kk][tm*4];
            *(float4*)&ar[4] = *(const float4*)&As[kk][64 + tm*4];
            *(float4*)&br[0] = *(const float4*)&Bs[kk][tn*4];
            *(float4*)&br[4] = *(const float4*)&Bs[kk][64 + tn*4];
            #pragma unroll
            for (int i = 0; i < 8; ++i)
                #pragma unroll
                for (int j = 0; j < 8; ++j)
                    acc[i][j] = fmaf(ar[i], br[j], acc[i][j]);
        }
        __syncthreads();
    }

    if (MODE == 0) {
        #pragma unroll
        for (int half = 0; half < 2; ++half) {
            const int col = n0 + half*64 + tn*4;
            const float4 bv = *(const float4*)&bias[col];
            #pragma unroll
            for (int i = 0; i < 8; ++i) {
                const int row = m0 + ((i < 4) ? (tm*4 + i) : (64 + tm*4 + i - 4));
                float4 o;
                o.x = acc[i][half*4+0] + bv.x;
                o.y = acc[i][half*4+1] + bv.y;
                o.z = acc[i][half*4+2] + bv.z;
                o.w = acc[i][half*4+3] + bv.w;
                *(float4*)(Cout + (size_t)row * NB + col) = o;
            }
        }
    } else {
        // columns j = c*768 + h*64 + s ; each 64-col half is one (c,h)
        #pragma unroll
        for (int half = 0; half < 2; ++half) {
            const int jbase = n0 + half*64;
            const int c  = jbase / DM;
            const int hh = (jbase % DM) >> 6;
            const int s0 = tn * 4;
            const float4 bv = *(const float4*)&bias[jbase + s0];
            #pragma unroll
            for (int i = 0; i < 8; ++i) {
                const int row = m0 + ((i < 4) ? (tm*4 + i) : (64 + tm*4 + i - 4));
                const int pp = row >> 10;
                const int nn = row & 1023;
                float v[4];
                v[0] = acc[i][half*4+0] + bv.x;
                v[1] = acc[i][half*4+1] + bv.y;
                v[2] = acc[i][half*4+2] + bv.z;
                v[3] = acc[i][half*4+3] + bv.w;
                const size_t head = (size_t)(pp*NH + hh);
                if (c == 2) {
                    // vT[p][h][s][n]
                    #pragma unroll
                    for (int j = 0; j < 4; ++j)
                        vtp[(head*HSZ + s0 + j)*NS + nn] = f2bf(v[j]);
                } else {
                    ushort hi[4], lo[4];
                    #pragma unroll
                    for (int j = 0; j < 4; ++j) {
                        hi[j] = f2bf(v[j]);
                        lo[j] = f2bf(v[j] - bf2f(hi[j]));
                    }
                    ushort* dh = (c == 0 ? qhp : khp) + (head*NS + nn)*HSZ + s0;
                    ushort* dl = (c == 0 ? qlp : klp) + (head*NS + nn)*HSZ + s0;
                    *(ushort4*)dh = ushort4{hi[0], hi[1], hi[2], hi[3]};
                    *(ushort4*)dl = ushort4{lo[0], lo[1], lo[2], lo[3]};
                }
            }
        }
    }
}

// ---------------- mask @ V per (p,h): mv[p][h][c] ----------------
__global__ void mv_kernel(const float* __restrict__ mask, const ushort* __restrict__ vt,
                          float* __restrict__ mv)
{
    const int ph = blockIdx.x;
    const int c  = threadIdx.x;      // 0..63
    const int p  = ph / NH;
    const ushort* vrow = vt + ((size_t)ph * HSZ + c) * NS;
    const float* mrow = mask + (size_t)p * NS;
    float acc = 0.f;
    for (int k = 0; k < NS; k += 4) {
        const ushort4 v4 = *(const ushort4*)(vrow + k);
        const float4  m4 = *(const float4*)(mrow + k);
        acc += m4.x * bf2f(v4.x) + m4.y * bf2f(v4.y)
             + m4.z * bf2f(v4.z) + m4.w * bf2f(v4.w);
    }
    mv[(size_t)ph * HSZ + c] = acc;
}

// ---------------- MFMA flash attention ----------------
// 4 waves/block; wave w owns q-rows [qt*64+w*16, +16). Q frags in registers.
// S = split-bf16 (hi*hi + hi*lo + lo*hi) QK^T via 16x16x32 MFMA; softmax on
// C-layout rows (width-16 shfl); P -> wave-private LDS -> A-layout; PV bf16.
// Post-softmax mask-add: ctx = O/l + mv[p][h][:] (precomputed mask@V).
__global__ __launch_bounds__(256, 2)
void attn_mfma_kernel(const ushort* __restrict__ qh, const ushort* __restrict__ ql,
                      const ushort* __restrict__ kh, const ushort* __restrict__ kl,
                      const ushort* __restrict__ vt, const float* __restrict__ mv,
                      float* __restrict__ ctx)
{
    __shared__ __align__(16) ushort pbuf[4][16][72];   // pitch 72: b128 reads conflict-free
    const int t    = threadIdx.x;
    const int w    = t >> 6;
    const int lane = t & 63;
    const int l15  = lane & 15;
    const int quad = lane >> 4;
    const int qt = blockIdx.x, h = blockIdx.y, p = blockIdx.z;

    const size_t headoff = ((size_t)p * NH + h) * (size_t)(NS * HSZ);

    // Q A-frags (persistent): row = qt*64 + w*16 + l15, k = k0 + quad*8 + j
    const ushort* qb_h = qh + headoff + (size_t)(qt*64 + w*16 + l15) * HSZ + quad*8;
    const ushort* qb_l = ql + headoff + (size_t)(qt*64 + w*16 + l15) * HSZ + quad*8;
    const bf16x8 aqh0 = *(const bf16x8*)(qb_h);
    const bf16x8 aqh1 = *(const bf16x8*)(qb_h + 32);
    const bf16x8 aql0 = *(const bf16x8*)(qb_l);
    const bf16x8 aql1 = *(const bf16x8*)(qb_l + 32);

    // K/V fragment base pointers (advance by k-tile)
    const ushort* kp_h = kh + headoff + (size_t)l15 * HSZ + quad*8;
    const ushort* kp_l = kl + headoff + (size_t)l15 * HSZ + quad*8;
    const ushort* vp   = vt + headoff + (size_t)l15 * NS  + quad*8;

    floatx4 o[4];
    float m_run[4], l_run[4];
    #pragma unroll
    for (int i = 0; i < 4; ++i) {
        o[i] = floatx4{0.f, 0.f, 0.f, 0.f};
        m_run[i] = -INFINITY;
        l_run[i] = 0.f;
    }

    for (int kt = 0; kt < 16; ++kt) {
        const size_t ko = (size_t)kt * 64 * HSZ;
        floatx4 s[4];
        #pragma unroll
        for (int tc = 0; tc < 4; ++tc) {
            const ushort* kb = kp_h + ko + (size_t)tc * 16 * HSZ;
            const ushort* lb = kp_l + ko + (size_t)tc * 16 * HSZ;
            const bf16x8 bh0 = *(const bf16x8*)(kb);
            const bf16x8 bh1 = *(const bf16x8*)(kb + 32);
            const bf16x8 bl0 = *(const bf16x8*)(lb);
            const bf16x8 bl1 = *(const bf16x8*)(lb + 32);
            floatx4 a = floatx4{0.f, 0.f, 0.f, 0.f};
            a = __builtin_amdgcn_mfma_f32_16x16x32_bf16(aqh0, bh0, a, 0, 0, 0);
            a = __builtin_amdgcn_mfma_f32_16x16x32_bf16(aqh1, bh1, a, 0, 0, 0);
            a = __builtin_amdgcn_mfma_f32_16x16x32_bf16(aql0, bh0, a, 0, 0, 0);
            a = __builtin_amdgcn_mfma_f32_16x16x32_bf16(aql1, bh1, a, 0, 0, 0);
            a = __builtin_amdgcn_mfma_f32_16x16x32_bf16(aqh0, bl0, a, 0, 0, 0);
            a = __builtin_amdgcn_mfma_f32_16x16x32_bf16(aqh1, bl1, a, 0, 0, 0);
            s[tc] = a;
        }
        #pragma unroll
        for (int tc = 0; tc < 4; ++tc) s[tc] *= SCL;

        // online softmax; row (quad*4+r) lives across the quad's 16 lanes
        #pragma unroll
        for (int r = 0; r < 4; ++r) {
            float lm = fmaxf(fmaxf(s[0][r], s[1][r]), fmaxf(s[2][r], s[3][r]));
            #pragma unroll
            for (int off = 1; off < 16; off <<= 1) lm = fmaxf(lm, __shfl_xor(lm, off, 16));
            const float mnew = fmaxf(m_run[r], lm);
            const float alpha = __expf(m_run[r] - mnew);
            m_run[r] = mnew;
            float ls = 0.f;
            #pragma unroll
            for (int tc = 0; tc < 4; ++tc) {
                const float pv = __expf(s[tc][r] - mnew);
                s[tc][r] = pv;
                ls += pv;
            }
            #pragma unroll
            for (int off = 1; off < 16; off <<= 1) ls += __shfl_xor(ls, off, 16);
            l_run[r] = l_run[r] * alpha + ls;
            o[0][r] *= alpha; o[1][r] *= alpha; o[2][r] *= alpha; o[3][r] *= alpha;
        }

        // P: C-layout -> wave-private LDS -> A-layout (in-wave LDS ordering)
        #pragma unroll
        for (int tc = 0; tc < 4; ++tc)
            #pragma unroll
            for (int r = 0; r < 4; ++r)
                pbuf[w][quad*4 + r][tc*16 + l15] = f2bf(s[tc][r]);

        const bf16x8 ap0 = *(const bf16x8*)&pbuf[w][l15][quad*8];
        const bf16x8 ap1 = *(const bf16x8*)&pbuf[w][l15][32 + quad*8];

        #pragma unroll
        for (int tc = 0; tc < 4; ++tc) {
            const ushort* vb = vp + (size_t)tc * 16 * NS + kt * 64;
            const bf16x8 bv0 = *(const bf16x8*)(vb);
            const bf16x8 bv1 = *(const bf16x8*)(vb + 32);
            o[tc] = __builtin_amdgcn_mfma_f32_16x16x32_bf16(ap0, bv0, o[tc], 0, 0, 0);
            o[tc] = __builtin_amdgcn_mfma_f32_16x16x32_bf16(ap1, bv1, o[tc], 0, 0, 0);
        }
    }

    // epilogue: ctx = O/l + mask@V
    const float* mvp = mv + ((size_t)p * NH + h) * HSZ;
    #pragma unroll
    for (int r = 0; r < 4; ++r) {
        const float inv = 1.0f / l_run[r];
        const int row = qt*64 + w*16 + quad*4 + r;
        float* crow = ctx + ((size_t)p * NS + row) * DM + h * 64;
        #pragma unroll
        for (int tc = 0; tc < 4; ++tc)
            crow[tc*16 + l15] = o[tc][r] * inv + mvp[tc*16 + l15];
    }
}

extern "C" void kernel_launch(void* const* d_in, const int* in_sizes, int n_in,
                              void* d_out, int out_size, void* d_ws, size_t ws_size,
                              hipStream_t stream)
{
    const float* x      = (const float*)d_in[0];
    const float* mask   = (const float*)d_in[1];
    const float* qkv_w  = (const float*)d_in[2];
    const float* qkv_b  = (const float*)d_in[3];
    const float* proj_w = (const float*)d_in[4];
    const float* proj_b = (const float*)d_in[5];
    float* out = (float*)d_out;

    // workspace: 5 bf16 arrays of (P,H,N,64) [vT is (P,H,64,N)] = 62.9 MB,
    // mv (P,H,64) fp32 = 24.6 KB, ctx (P,N,D) fp32 = 25.2 MB  => ~88 MB
    const size_t HE = (size_t)PB * NH * NS * HSZ;
    ushort* qh = (ushort*)d_ws;
    ushort* ql = qh + HE;
    ushort* kh = ql + HE;
    ushort* kl = kh + HE;
    ushort* vt = kl + HE;
    float*  mv = (float*)(vt + HE);
    float* ctx = mv + (size_t)PB * NH * HSZ;

    gemm_kernel<1><<<dim3(3*DM/128, PB*NS/128), 256, 0, stream>>>(
        x, qkv_w, qkv_b, nullptr, qh, ql, kh, kl, vt, PB*NS, DM, 3*DM);
    mv_kernel<<<dim3(PB*NH), 64, 0, stream>>>(mask, vt, mv);
    attn_mfma_kernel<<<dim3(NS/64, NH, PB), 256, 0, stream>>>(
        qh, ql, kh, kl, vt, mv, ctx);
    gemm_kernel<0><<<dim3(DM/128, PB*NS/128), 256, 0, stream>>>(
        ctx, proj_w, proj_b, out, nullptr, nullptr, nullptr, nullptr, nullptr,
        PB*NS, DM, DM);
}

// Round 3
// 507.950 us; speedup vs baseline: 1.8842x; 1.6829x over previous
//
#include <hip/hip_runtime.h>
#include <hip/hip_bf16.h>
#include <cstdint>
#include <math.h>

constexpr int PB = 8;
constexpr int NS = 1024;
constexpr int DM = 768;
constexpr int NH = 12;
constexpr int HSZ = 64;
constexpr float SCL = 8.0f;   // reference MULTIPLIES by sqrt(head_size)

typedef short bf16x8 __attribute__((ext_vector_type(8)));
typedef float floatx4 __attribute__((ext_vector_type(4)));

__device__ __forceinline__ ushort f2bf(float x) {
    __hip_bfloat16 b = __float2bfloat16(x);
    return *reinterpret_cast<ushort*>(&b);
}
__device__ __forceinline__ float bf2f(ushort u) {
    __hip_bfloat16 b = *reinterpret_cast<__hip_bfloat16*>(&u);
    return __bfloat162float(b);
}

#define GLDS(g, l)                                                             \
    __builtin_amdgcn_global_load_lds(                                          \
        (const __attribute__((address_space(1))) void*)(g),                    \
        (__attribute__((address_space(3))) void*)(l), 16, 0, 0)

// ---------------- split fp32 -> (hi, lo) bf16, elementwise ----------------
__global__ void split_kernel(const float* __restrict__ x, ushort* __restrict__ hi,
                             ushort* __restrict__ lo, int n4)
{
    int i = blockIdx.x * blockDim.x + threadIdx.x;
    const int stride = gridDim.x * blockDim.x;
    for (; i < n4; i += stride) {
        const float4 v = ((const float4*)x)[i];
        ushort4 h, l;
        h.x = f2bf(v.x); l.x = f2bf(v.x - bf2f(h.x));
        h.y = f2bf(v.y); l.y = f2bf(v.y - bf2f(h.y));
        h.z = f2bf(v.z); l.z = f2bf(v.z - bf2f(h.z));
        h.w = f2bf(v.w); l.w = f2bf(v.w - bf2f(h.w));
        ((ushort4*)hi)[i] = h;
        ((ushort4*)lo)[i] = l;
    }
}

// ------------- split + transpose: w (K x N) -> wT hi/lo (N x K) -------------
__global__ void splitT_kernel(const float* __restrict__ w, ushort* __restrict__ hiT,
                              ushort* __restrict__ loT, int K, int N)
{
    __shared__ float tile[32][33];
    const int tx = threadIdx.x, ty = threadIdx.y;   // (32, 8)
    const int bx = blockIdx.x, by = blockIdx.y;     // N/32, K/32
    #pragma unroll
    for (int r = 0; r < 4; ++r)
        tile[ty + r*8][tx] = w[(size_t)(by*32 + ty + r*8) * N + bx*32 + tx];
    __syncthreads();
    #pragma unroll
    for (int r = 0; r < 4; ++r) {
        const int n = bx*32 + ty + r*8;
        const int k = by*32 + tx;
        const float v = tile[tx][ty + r*8];
        const ushort h = f2bf(v);
        hiT[(size_t)n * K + k] = h;
        loT[(size_t)n * K + k] = f2bf(v - bf2f(h));
    }
}

// ---------------- split-bf16 MFMA GEMM ----------------
// C = A(MxK) @ B(KxN) via hi*hi + hi*lo + lo*hi. A given as hi/lo bf16
// row-major (MxK); B given TRANSPOSED hi/lo bf16 (NxK). 128x128 tile, BK=32,
// 4 waves (2x2), each wave 4x4 grid of 16x16x32 MFMA tiles.
// Staging: global_load_lds width=16, XOR k-seg swizzle (4-way LDS read max).
// MODE 0: fp32 store out[M][DM]. MODE 1: qkv scatter q/k hi/lo + vT (bf16).
template <int MODE>
__global__ __launch_bounds__(256, 2)
void gemm_bf16s(const ushort* __restrict__ Ah, const ushort* __restrict__ Al,
                const ushort* __restrict__ Bh, const ushort* __restrict__ Bl,
                const float* __restrict__ bias, float* __restrict__ outf,
                ushort* __restrict__ qh, ushort* __restrict__ ql,
                ushort* __restrict__ kh, ushort* __restrict__ kl,
                ushort* __restrict__ vt, int K)
{
    __shared__ __align__(16) ushort Ah_s[128*32];
    __shared__ __align__(16) ushort Al_s[128*32];
    __shared__ __align__(16) ushort Bh_s[128*32];
    __shared__ __align__(16) ushort Bl_s[128*32];

    const int t    = threadIdx.x;
    const int w    = t >> 6;
    const int lane = t & 63;
    const int l15  = lane & 15;
    const int quad = lane >> 4;
    const int wm = w >> 1, wn = w & 1;
    const int m0 = blockIdx.y * 128, n0 = blockIdx.x * 128;

    floatx4 acc[4][4];
    #pragma unroll
    for (int i = 0; i < 4; ++i)
        #pragma unroll
        for (int j = 0; j < 4; ++j) acc[i][j] = floatx4{0.f, 0.f, 0.f, 0.f};

    // staging geometry: wave w stages rows [w*32, w*32+32) of each array.
    // lane i -> row (i>>2), k-seg ((i&3) ^ ((i>>2)&3))  [XOR swizzle]
    const int srow = lane >> 2;
    const int sseg = (lane & 3) ^ (srow & 3);
    const int r0   = w * 32;
    const size_t aBase = (size_t)(m0 + r0 + srow) * K + sseg * 8;
    const size_t bBase = (size_t)(n0 + r0 + srow) * K + sseg * 8;
    const int ldsBase = r0 * 32;
    const int fsl = (quad ^ (l15 & 3)) * 8;   // frag read slot (unswizzle)

    for (int k0 = 0; k0 < K; k0 += 32) {
        #pragma unroll
        for (int j = 0; j < 2; ++j) {
            const size_t ga = aBase + (size_t)j * 16 * K + k0;
            const size_t gb = bBase + (size_t)j * 16 * K + k0;
            const int lb = ldsBase + j * 512;
            GLDS(Ah + ga, Ah_s + lb);
            GLDS(Al + ga, Al_s + lb);
            GLDS(Bh + gb, Bh_s + lb);
            GLDS(Bl + gb, Bl_s + lb);
        }
        __syncthreads();

        bf16x8 fah[4], fal[4], fbh[4], fbl[4];
        #pragma unroll
        for (int i = 0; i < 4; ++i) {
            const int ra = (wm*64 + i*16 + l15) * 32 + fsl;
            fah[i] = *(const bf16x8*)(Ah_s + ra);
            fal[i] = *(const bf16x8*)(Al_s + ra);
            const int rb = (wn*64 + i*16 + l15) * 32 + fsl;
            fbh[i] = *(const bf16x8*)(Bh_s + rb);
            fbl[i] = *(const bf16x8*)(Bl_s + rb);
        }
        #pragma unroll
        for (int mt = 0; mt < 4; ++mt)
            #pragma unroll
            for (int nt = 0; nt < 4; ++nt) {
                acc[mt][nt] = __builtin_amdgcn_mfma_f32_16x16x32_bf16(fah[mt], fbh[nt], acc[mt][nt], 0, 0, 0);
                acc[mt][nt] = __builtin_amdgcn_mfma_f32_16x16x32_bf16(fah[mt], fbl[nt], acc[mt][nt], 0, 0, 0);
                acc[mt][nt] = __builtin_amdgcn_mfma_f32_16x16x32_bf16(fal[mt], fbh[nt], acc[mt][nt], 0, 0, 0);
            }
        __syncthreads();
    }

    if (MODE == 0) {
        #pragma unroll
        for (int nt = 0; nt < 4; ++nt) {
            const int col = n0 + wn*64 + nt*16 + l15;
            const float bval = bias[col];
            #pragma unroll
            for (int mt = 0; mt < 4; ++mt) {
                const int row0 = m0 + wm*64 + mt*16 + quad*4;
                #pragma unroll
                for (int r = 0; r < 4; ++r)
                    outf[(size_t)(row0 + r) * DM + col] = acc[mt][nt][r] + bval;
            }
        }
    } else {
        // N-cols here are j = c*768 + h*64 + s; each wave's 64-col span is one (c,h)
        const int jbase = n0 + wn*64;
        const int c  = jbase / DM;
        const int hh = (jbase % DM) >> 6;
        const int pp = (m0 + wm*64) >> 10;
        const size_t head = (size_t)pp * NH + hh;
        #pragma unroll
        for (int nt = 0; nt < 4; ++nt) {
            const int s = nt*16 + l15;
            const float bval = bias[jbase + s];
            #pragma unroll
            for (int mt = 0; mt < 4; ++mt) {
                const int tok0 = m0 + wm*64 + mt*16 + quad*4;
                const int nn0  = tok0 & 1023;
                if (c == 2) {
                    ushort4 pk;
                    pk.x = f2bf(acc[mt][nt][0] + bval);
                    pk.y = f2bf(acc[mt][nt][1] + bval);
                    pk.z = f2bf(acc[mt][nt][2] + bval);
                    pk.w = f2bf(acc[mt][nt][3] + bval);
                    *(ushort4*)(vt + (head*HSZ + s) * NS + nn0) = pk;
                } else {
                    ushort* dh = (c == 0 ? qh : kh);
                    ushort* dl = (c == 0 ? ql : kl);
                    #pragma unroll
                    for (int r = 0; r < 4; ++r) {
                        const float v = acc[mt][nt][r] + bval;
                        const ushort hi = f2bf(v);
                        dh[(head*NS + nn0 + r) * HSZ + s] = hi;
                        dl[(head*NS + nn0 + r) * HSZ + s] = f2bf(v - bf2f(hi));
                    }
                }
            }
        }
    }
}

// ---------------- mask @ V per (p,h): mv[p][h][c] ----------------
__global__ void mv_kernel(const float* __restrict__ mask, const ushort* __restrict__ vt,
                          float* __restrict__ mv)
{
    __shared__ float red[4][64];
    const int ph = blockIdx.x;
    const int t  = threadIdx.x;
    const int c  = t & 63, part = t >> 6;
    const ushort* vrow = vt + ((size_t)ph * HSZ + c) * NS + part * 256;
    const float*  mrow = mask + (size_t)(ph / NH) * NS + part * 256;
    float acc = 0.f;
    for (int k = 0; k < 256; k += 4) {
        const ushort4 v4 = *(const ushort4*)(vrow + k);
        const float4  m4 = *(const float4*)(mrow + k);
        acc += m4.x * bf2f(v4.x) + m4.y * bf2f(v4.y)
             + m4.z * bf2f(v4.z) + m4.w * bf2f(v4.w);
    }
    red[part][c] = acc;
    __syncthreads();
    if (t < 64)
        mv[(size_t)ph * HSZ + t] = red[0][t] + red[1][t] + red[2][t] + red[3][t];
}

// ---------------- MFMA flash attention ----------------
// 4 waves/block; wave w owns q-rows [qt*64+w*16, +16). Q frags in registers.
// S = split-bf16 QK^T; softmax on C-layout rows; P via wave-private LDS; PV bf16.
// Epilogue writes ctx as split hi/lo bf16 (consumed by proj MFMA GEMM):
// ctx = O/l + mv[p][h][:] (precomputed mask@V, post-softmax mask-add exact).
__global__ __launch_bounds__(256, 2)
void attn_mfma_kernel(const ushort* __restrict__ qh, const ushort* __restrict__ ql,
                      const ushort* __restrict__ kh, const ushort* __restrict__ kl,
                      const ushort* __restrict__ vt, const float* __restrict__ mv,
                      ushort* __restrict__ ctxh, ushort* __restrict__ ctxl)
{
    __shared__ __align__(16) ushort pbuf[4][16][72];
    const int t    = threadIdx.x;
    const int w    = t >> 6;
    const int lane = t & 63;
    const int l15  = lane & 15;
    const int quad = lane >> 4;
    const int qt = blockIdx.x, h = blockIdx.y, p = blockIdx.z;

    const size_t headoff = ((size_t)p * NH + h) * (size_t)(NS * HSZ);

    const ushort* qb_h = qh + headoff + (size_t)(qt*64 + w*16 + l15) * HSZ + quad*8;
    const ushort* qb_l = ql + headoff + (size_t)(qt*64 + w*16 + l15) * HSZ + quad*8;
    const bf16x8 aqh0 = *(const bf16x8*)(qb_h);
    const bf16x8 aqh1 = *(const bf16x8*)(qb_h + 32);
    const bf16x8 aql0 = *(const bf16x8*)(qb_l);
    const bf16x8 aql1 = *(const bf16x8*)(qb_l + 32);

    const ushort* kp_h = kh + headoff + (size_t)l15 * HSZ + quad*8;
    const ushort* kp_l = kl + headoff + (size_t)l15 * HSZ + quad*8;
    const ushort* vp   = vt + headoff + (size_t)l15 * NS  + quad*8;

    floatx4 o[4];
    float m_run[4], l_run[4];
    #pragma unroll
    for (int i = 0; i < 4; ++i) {
        o[i] = floatx4{0.f, 0.f, 0.f, 0.f};
        m_run[i] = -INFINITY;
        l_run[i] = 0.f;
    }

    for (int kt = 0; kt < 16; ++kt) {
        const size_t ko = (size_t)kt * 64 * HSZ;
        floatx4 s[4];
        #pragma unroll
        for (int tc = 0; tc < 4; ++tc) {
            const ushort* kb = kp_h + ko + (size_t)tc * 16 * HSZ;
            const ushort* lb = kp_l + ko + (size_t)tc * 16 * HSZ;
            const bf16x8 bh0 = *(const bf16x8*)(kb);
            const bf16x8 bh1 = *(const bf16x8*)(kb + 32);
            const bf16x8 bl0 = *(const bf16x8*)(lb);
            const bf16x8 bl1 = *(const bf16x8*)(lb + 32);
            floatx4 a = floatx4{0.f, 0.f, 0.f, 0.f};
            a = __builtin_amdgcn_mfma_f32_16x16x32_bf16(aqh0, bh0, a, 0, 0, 0);
            a = __builtin_amdgcn_mfma_f32_16x16x32_bf16(aqh1, bh1, a, 0, 0, 0);
            a = __builtin_amdgcn_mfma_f32_16x16x32_bf16(aql0, bh0, a, 0, 0, 0);
            a = __builtin_amdgcn_mfma_f32_16x16x32_bf16(aql1, bh1, a, 0, 0, 0);
            a = __builtin_amdgcn_mfma_f32_16x16x32_bf16(aqh0, bl0, a, 0, 0, 0);
            a = __builtin_amdgcn_mfma_f32_16x16x32_bf16(aqh1, bl1, a, 0, 0, 0);
            s[tc] = a;
        }
        #pragma unroll
        for (int tc = 0; tc < 4; ++tc) s[tc] *= SCL;

        #pragma unroll
        for (int r = 0; r < 4; ++r) {
            float lm = fmaxf(fmaxf(s[0][r], s[1][r]), fmaxf(s[2][r], s[3][r]));
            #pragma unroll
            for (int off = 1; off < 16; off <<= 1) lm = fmaxf(lm, __shfl_xor(lm, off, 16));
            const float mnew = fmaxf(m_run[r], lm);
            const float alpha = __expf(m_run[r] - mnew);
            m_run[r] = mnew;
            float ls = 0.f;
            #pragma unroll
            for (int tc = 0; tc < 4; ++tc) {
                const float pv = __expf(s[tc][r] - mnew);
                s[tc][r] = pv;
                ls += pv;
            }
            #pragma unroll
            for (int off = 1; off < 16; off <<= 1) ls += __shfl_xor(ls, off, 16);
            l_run[r] = l_run[r] * alpha + ls;
            o[0][r] *= alpha; o[1][r] *= alpha; o[2][r] *= alpha; o[3][r] *= alpha;
        }

        #pragma unroll
        for (int tc = 0; tc < 4; ++tc)
            #pragma unroll
            for (int r = 0; r < 4; ++r)
                pbuf[w][quad*4 + r][tc*16 + l15] = f2bf(s[tc][r]);

        const bf16x8 ap0 = *(const bf16x8*)&pbuf[w][l15][quad*8];
        const bf16x8 ap1 = *(const bf16x8*)&pbuf[w][l15][32 + quad*8];

        #pragma unroll
        for (int tc = 0; tc < 4; ++tc) {
            const ushort* vb = vp + (size_t)tc * 16 * NS + kt * 64;
            const bf16x8 bv0 = *(const bf16x8*)(vb);
            const bf16x8 bv1 = *(const bf16x8*)(vb + 32);
            o[tc] = __builtin_amdgcn_mfma_f32_16x16x32_bf16(ap0, bv0, o[tc], 0, 0, 0);
            o[tc] = __builtin_amdgcn_mfma_f32_16x16x32_bf16(ap1, bv1, o[tc], 0, 0, 0);
        }
    }

    const float* mvp = mv + ((size_t)p * NH + h) * HSZ;
    #pragma unroll
    for (int r = 0; r < 4; ++r) {
        const float inv = 1.0f / l_run[r];
        const int row = qt*64 + w*16 + quad*4 + r;
        const size_t base = ((size_t)p * NS + row) * DM + h * 64;
        #pragma unroll
        for (int tc = 0; tc < 4; ++tc) {
            const float v = o[tc][r] * inv + mvp[tc*16 + l15];
            const ushort hi = f2bf(v);
            ctxh[base + tc*16 + l15] = hi;
            ctxl[base + tc*16 + l15] = f2bf(v - bf2f(hi));
        }
    }
}

extern "C" void kernel_launch(void* const* d_in, const int* in_sizes, int n_in,
                              void* d_out, int out_size, void* d_ws, size_t ws_size,
                              hipStream_t stream)
{
    const float* x      = (const float*)d_in[0];
    const float* mask   = (const float*)d_in[1];
    const float* qkv_w  = (const float*)d_in[2];
    const float* qkv_b  = (const float*)d_in[3];
    const float* proj_w = (const float*)d_in[4];
    const float* proj_b = (const float*)d_in[5];
    float* out = (float*)d_out;

    // workspace (~97.5 MB): x hi/lo is dead after qkv GEMM, so ctx aliases it.
    const size_t HE = (size_t)PB * NH * NS * HSZ;   // 6291456
    const size_t QW = (size_t)DM * 3 * DM;          // 1769472
    const size_t PW = (size_t)DM * DM;              // 589824
    ushort* xh  = (ushort*)d_ws;
    ushort* xl  = xh + HE;
    ushort* qwh = xl + HE;
    ushort* qwl = qwh + QW;
    ushort* pwh = qwl + QW;
    ushort* pwl = pwh + PW;
    ushort* qhv = pwl + PW;
    ushort* qlv = qhv + HE;
    ushort* khv = qlv + HE;
    ushort* klv = khv + HE;
    ushort* vtv = klv + HE;
    float*  mvb = (float*)(vtv + HE);
    ushort* cth = xh;   // alias: ctx hi/lo over x hi/lo
    ushort* ctl = xl;

    split_kernel<<<2048, 256, 0, stream>>>(x, xh, xl, (int)(HE / 4));
    splitT_kernel<<<dim3(3*DM/32, DM/32), dim3(32, 8), 0, stream>>>(qkv_w, qwh, qwl, DM, 3*DM);
    splitT_kernel<<<dim3(DM/32,   DM/32), dim3(32, 8), 0, stream>>>(proj_w, pwh, pwl, DM, DM);

    gemm_bf16s<1><<<dim3(3*DM/128, PB*NS/128), 256, 0, stream>>>(
        xh, xl, qwh, qwl, qkv_b, nullptr, qhv, qlv, khv, klv, vtv, DM);

    mv_kernel<<<dim3(PB*NH), 256, 0, stream>>>(mask, vtv, mvb);

    attn_mfma_kernel<<<dim3(NS/64, NH, PB), 256, 0, stream>>>(
        qhv, qlv, khv, klv, vtv, mvb, cth, ctl);

    gemm_bf16s<0><<<dim3(DM/128, PB*NS/128), 256, 0, stream>>>(
        cth, ctl, pwh, pwl, proj_b, out, nullptr, nullptr, nullptr, nullptr, nullptr, DM);
}

// Round 4
// 345.282 us; speedup vs baseline: 2.7719x; 1.4711x over previous
//
#include <hip/hip_runtime.h>
#include <hip/hip_bf16.h>
#include <cstdint>
#include <math.h>

constexpr int PB = 8;
constexpr int NS = 1024;
constexpr int DM = 768;
constexpr int NH = 12;
constexpr int HSZ = 64;
// NOTE: reference MULTIPLIES scores by sqrt(head_size)=8. We fold the *8 into
// q at the qkv epilogue (exact: power of two), so attn needs no scale step.

typedef short bf16x8 __attribute__((ext_vector_type(8)));
typedef float floatx4 __attribute__((ext_vector_type(4)));

__device__ __forceinline__ ushort f2bf(float x) {
    __hip_bfloat16 b = __float2bfloat16(x);
    return *reinterpret_cast<ushort*>(&b);
}
__device__ __forceinline__ float bf2f(ushort u) {
    __hip_bfloat16 b = *reinterpret_cast<__hip_bfloat16*>(&u);
    return __bfloat162float(b);
}

#define GLDS(g, l)                                                             \
    __builtin_amdgcn_global_load_lds(                                          \
        (const __attribute__((address_space(1))) void*)(g),                    \
        (__attribute__((address_space(3))) void*)(l), 16, 0, 0)

// ---------------- split fp32 -> (hi, lo) bf16, elementwise ----------------
__global__ void split_kernel(const float* __restrict__ x, ushort* __restrict__ hi,
                             ushort* __restrict__ lo, int n4)
{
    int i = blockIdx.x * blockDim.x + threadIdx.x;
    const int stride = gridDim.x * blockDim.x;
    for (; i < n4; i += stride) {
        const float4 v = ((const float4*)x)[i];
        ushort4 h, l;
        h.x = f2bf(v.x); l.x = f2bf(v.x - bf2f(h.x));
        h.y = f2bf(v.y); l.y = f2bf(v.y - bf2f(h.y));
        h.z = f2bf(v.z); l.z = f2bf(v.z - bf2f(h.z));
        h.w = f2bf(v.w); l.w = f2bf(v.w - bf2f(h.w));
        ((ushort4*)hi)[i] = h;
        ((ushort4*)lo)[i] = l;
    }
}

// ------------- split + transpose: w (K x N) -> wT hi/lo (N x K) -------------
__global__ void splitT_kernel(const float* __restrict__ w, ushort* __restrict__ hiT,
                              ushort* __restrict__ loT, int K, int N)
{
    __shared__ float tile[32][33];
    const int tx = threadIdx.x, ty = threadIdx.y;   // (32, 8)
    const int bx = blockIdx.x, by = blockIdx.y;     // N/32, K/32
    #pragma unroll
    for (int r = 0; r < 4; ++r)
        tile[ty + r*8][tx] = w[(size_t)(by*32 + ty + r*8) * N + bx*32 + tx];
    __syncthreads();
    #pragma unroll
    for (int r = 0; r < 4; ++r) {
        const int n = bx*32 + ty + r*8;
        const int k = by*32 + tx;
        const float v = tile[tx][ty + r*8];
        const ushort h = f2bf(v);
        hiT[(size_t)n * K + k] = h;
        loT[(size_t)n * K + k] = f2bf(v - bf2f(h));
    }
}

// ---------------- split-bf16 MFMA GEMM ----------------
// C = A(MxK) @ B(KxN) via hi*hi + hi*lo + lo*hi. A hi/lo bf16 row-major;
// B TRANSPOSED hi/lo (NxK). 128x128 tile, BK=32, 4 waves, 4x4 MFMA tiles.
// MODE 0: fp32 store. MODE 1: qkv scatter (q scaled by 8) + vT.
template <int MODE>
__global__ __launch_bounds__(256, 2)
void gemm_bf16s(const ushort* __restrict__ Ah, const ushort* __restrict__ Al,
                const ushort* __restrict__ Bh, const ushort* __restrict__ Bl,
                const float* __restrict__ bias, float* __restrict__ outf,
                ushort* __restrict__ qh, ushort* __restrict__ ql,
                ushort* __restrict__ kh, ushort* __restrict__ kl,
                ushort* __restrict__ vt, int K)
{
    __shared__ __align__(16) ushort Ah_s[128*32];
    __shared__ __align__(16) ushort Al_s[128*32];
    __shared__ __align__(16) ushort Bh_s[128*32];
    __shared__ __align__(16) ushort Bl_s[128*32];

    const int t    = threadIdx.x;
    const int w    = t >> 6;
    const int lane = t & 63;
    const int l15  = lane & 15;
    const int quad = lane >> 4;
    const int wm = w >> 1, wn = w & 1;
    const int m0 = blockIdx.y * 128, n0 = blockIdx.x * 128;

    floatx4 acc[4][4];
    #pragma unroll
    for (int i = 0; i < 4; ++i)
        #pragma unroll
        for (int j = 0; j < 4; ++j) acc[i][j] = floatx4{0.f, 0.f, 0.f, 0.f};

    const int srow = lane >> 2;
    const int sseg = (lane & 3) ^ (srow & 3);
    const int r0   = w * 32;
    const size_t aBase = (size_t)(m0 + r0 + srow) * K + sseg * 8;
    const size_t bBase = (size_t)(n0 + r0 + srow) * K + sseg * 8;
    const int ldsBase = r0 * 32;
    const int fsl = (quad ^ (l15 & 3)) * 8;

    for (int k0 = 0; k0 < K; k0 += 32) {
        #pragma unroll
        for (int j = 0; j < 2; ++j) {
            const size_t ga = aBase + (size_t)j * 16 * K + k0;
            const size_t gb = bBase + (size_t)j * 16 * K + k0;
            const int lb = ldsBase + j * 512;
            GLDS(Ah + ga, Ah_s + lb);
            GLDS(Al + ga, Al_s + lb);
            GLDS(Bh + gb, Bh_s + lb);
            GLDS(Bl + gb, Bl_s + lb);
        }
        __syncthreads();

        bf16x8 fah[4], fal[4], fbh[4], fbl[4];
        #pragma unroll
        for (int i = 0; i < 4; ++i) {
            const int ra = (wm*64 + i*16 + l15) * 32 + fsl;
            fah[i] = *(const bf16x8*)(Ah_s + ra);
            fal[i] = *(const bf16x8*)(Al_s + ra);
            const int rb = (wn*64 + i*16 + l15) * 32 + fsl;
            fbh[i] = *(const bf16x8*)(Bh_s + rb);
            fbl[i] = *(const bf16x8*)(Bl_s + rb);
        }
        #pragma unroll
        for (int mt = 0; mt < 4; ++mt)
            #pragma unroll
            for (int nt = 0; nt < 4; ++nt) {
                acc[mt][nt] = __builtin_amdgcn_mfma_f32_16x16x32_bf16(fah[mt], fbh[nt], acc[mt][nt], 0, 0, 0);
                acc[mt][nt] = __builtin_amdgcn_mfma_f32_16x16x32_bf16(fah[mt], fbl[nt], acc[mt][nt], 0, 0, 0);
                acc[mt][nt] = __builtin_amdgcn_mfma_f32_16x16x32_bf16(fal[mt], fbh[nt], acc[mt][nt], 0, 0, 0);
            }
        __syncthreads();
    }

    if (MODE == 0) {
        #pragma unroll
        for (int nt = 0; nt < 4; ++nt) {
            const int col = n0 + wn*64 + nt*16 + l15;
            const float bval = bias[col];
            #pragma unroll
            for (int mt = 0; mt < 4; ++mt) {
                const int row0 = m0 + wm*64 + mt*16 + quad*4;
                #pragma unroll
                for (int r = 0; r < 4; ++r)
                    outf[(size_t)(row0 + r) * DM + col] = acc[mt][nt][r] + bval;
            }
        }
    } else {
        const int jbase = n0 + wn*64;
        const int c  = jbase / DM;
        const int hh = (jbase % DM) >> 6;
        const int pp = (m0 + wm*64) >> 10;
        const size_t head = (size_t)pp * NH + hh;
        #pragma unroll
        for (int nt = 0; nt < 4; ++nt) {
            const int s = nt*16 + l15;
            const float bval = bias[jbase + s];
            #pragma unroll
            for (int mt = 0; mt < 4; ++mt) {
                const int tok0 = m0 + wm*64 + mt*16 + quad*4;
                const int nn0  = tok0 & 1023;
                if (c == 2) {
                    ushort4 pk;
                    pk.x = f2bf(acc[mt][nt][0] + bval);
                    pk.y = f2bf(acc[mt][nt][1] + bval);
                    pk.z = f2bf(acc[mt][nt][2] + bval);
                    pk.w = f2bf(acc[mt][nt][3] + bval);
                    *(ushort4*)(vt + (head*HSZ + s) * NS + nn0) = pk;
                } else {
                    ushort* dh = (c == 0 ? qh : kh);
                    ushort* dl = (c == 0 ? ql : kl);
                    const float qscale = (c == 0) ? 8.0f : 1.0f;   // fold SCL into q (exact)
                    #pragma unroll
                    for (int r = 0; r < 4; ++r) {
                        const float v = (acc[mt][nt][r] + bval) * qscale;
                        const ushort hi = f2bf(v);
                        dh[(head*NS + nn0 + r) * HSZ + s] = hi;
                        dl[(head*NS + nn0 + r) * HSZ + s] = f2bf(v - bf2f(hi));
                    }
                }
            }
        }
    }
}

// ---------------- mask @ V per (p,h): mv[p][h][c] ----------------
__global__ void mv_kernel(const float* __restrict__ mask, const ushort* __restrict__ vt,
                          float* __restrict__ mv)
{
    __shared__ float red[4][64];
    const int ph = blockIdx.x;
    const int t  = threadIdx.x;
    const int c  = t & 63, part = t >> 6;
    const ushort* vrow = vt + ((size_t)ph * HSZ + c) * NS + part * 256;
    const float*  mrow = mask + (size_t)(ph / NH) * NS + part * 256;
    float acc = 0.f;
    for (int k = 0; k < 256; k += 4) {
        const ushort4 v4 = *(const ushort4*)(vrow + k);
        const float4  m4 = *(const float4*)(mrow + k);
        acc += m4.x * bf2f(v4.x) + m4.y * bf2f(v4.y)
             + m4.z * bf2f(v4.z) + m4.w * bf2f(v4.w);
    }
    red[part][c] = acc;
    __syncthreads();
    if (t < 64)
        mv[(size_t)ph * HSZ + t] = red[0][t] + red[1][t] + red[2][t] + red[3][t];
}

// ---------------- MFMA flash attention, LDS-staged K/V ----------------
// Block = 128 q-rows x (p,h); 4 waves, wave w owns rows [w*32, w*32+32).
// Per k-tile (64 cols): K_hi/K_lo/V staged into LDS by global_load_lds w=16
// with XOR seg-swizzle on the GLOBAL address (LDS dest must stay lane-linear);
// B-frag ds_read_b128 then hits all 8 bank-groups evenly (8 dwords/bank).
// Q (pre-scaled by 8) hi/lo frags persistent in registers. Softmax on C-layout
// rows via width-16 shfl; P via wave-private padded LDS; PV bf16 MFMA.
// ctx = O/l + mv (precomputed mask@V => exact post-softmax mask-add), stored
// as split hi/lo bf16 for the proj MFMA GEMM.
__global__ __launch_bounds__(256, 3)
void attn_mfma_kernel(const ushort* __restrict__ qh, const ushort* __restrict__ ql,
                      const ushort* __restrict__ kh, const ushort* __restrict__ kl,
                      const ushort* __restrict__ vt, const float* __restrict__ mv,
                      ushort* __restrict__ ctxh, ushort* __restrict__ ctxl)
{
    __shared__ __align__(16) ushort khs[64*64];
    __shared__ __align__(16) ushort kls[64*64];
    __shared__ __align__(16) ushort vs [64*64];
    __shared__ __align__(16) ushort pbuf[4][32*72];   // pitch 72: balanced b128

    const int t    = threadIdx.x;
    const int w    = t >> 6;
    const int lane = t & 63;
    const int l15  = lane & 15;
    const int quad = lane >> 4;
    const int qt = blockIdx.x, h = blockIdx.y, p = blockIdx.z;
    const size_t headoff = ((size_t)p * NH + h) * (size_t)(NS * HSZ);

    // persistent Q A-frags: row = qt*128 + w*32 + rt*16 + l15, k = quad*8(+32)
    bf16x8 aqh[2][2], aql[2][2];
    #pragma unroll
    for (int rt = 0; rt < 2; ++rt) {
        const size_t r = (size_t)(qt*128 + w*32 + rt*16 + l15);
        const ushort* bh = qh + headoff + r * HSZ + quad*8;
        const ushort* bl = ql + headoff + r * HSZ + quad*8;
        aqh[rt][0] = *(const bf16x8*)(bh);
        aqh[rt][1] = *(const bf16x8*)(bh + 32);
        aql[rt][0] = *(const bf16x8*)(bl);
        aql[rt][1] = *(const bf16x8*)(bl + 32);
    }

    floatx4 o[2][4];
    float m_run[2][4], l_run[2][4];
    #pragma unroll
    for (int rt = 0; rt < 2; ++rt)
        #pragma unroll
        for (int i = 0; i < 4; ++i) {
            o[rt][i] = floatx4{0.f, 0.f, 0.f, 0.f};
            m_run[rt][i] = -INFINITY;
            l_run[rt][i] = 0.f;
        }

    const int srow8 = lane >> 3;   // staging: lane -> row-in-8, slot
    const int sslot = lane & 7;

    for (int kt = 0; kt < 16; ++kt) {
        __syncthreads();   // previous tile's LDS reads complete
        #pragma unroll
        for (int j = 0; j < 2; ++j) {
            const int row = w*16 + j*8 + srow8;          // tile-local 0..63
            const int seg = sslot ^ (row & 7);           // XOR swizzle (global side)
            const size_t gk = headoff + (size_t)(kt*64 + row) * HSZ + seg*8;
            const size_t gv = headoff + (size_t)row * NS + kt*64 + seg*8;
            const int ldst = (w*16 + j*8) * 64;          // wave-uniform LDS base
            GLDS(kh + gk, khs + ldst);
            GLDS(kl + gk, kls + ldst);
            GLDS(vt + gv, vs  + ldst);
        }
        __syncthreads();   // staged data visible

        // S = Q K^T (split: qh*kh + qh*kl + ql*kh), q pre-scaled by 8
        floatx4 s[2][4];
        #pragma unroll
        for (int tc = 0; tc < 4; ++tc) {
            const int a0 = (tc*16 + l15)*64 + ((quad       ^ (l15 & 7)) * 8);
            const int a1 = (tc*16 + l15)*64 + (((quad + 4) ^ (l15 & 7)) * 8);
            const bf16x8 bh0 = *(const bf16x8*)(khs + a0);
            const bf16x8 bh1 = *(const bf16x8*)(khs + a1);
            const bf16x8 bl0 = *(const bf16x8*)(kls + a0);
            const bf16x8 bl1 = *(const bf16x8*)(kls + a1);
            #pragma unroll
            for (int rt = 0; rt < 2; ++rt) {
                floatx4 a = floatx4{0.f, 0.f, 0.f, 0.f};
                a = __builtin_amdgcn_mfma_f32_16x16x32_bf16(aqh[rt][0], bh0, a, 0, 0, 0);
                a = __builtin_amdgcn_mfma_f32_16x16x32_bf16(aqh[rt][1], bh1, a, 0, 0, 0);
                a = __builtin_amdgcn_mfma_f32_16x16x32_bf16(aql[rt][0], bh0, a, 0, 0, 0);
                a = __builtin_amdgcn_mfma_f32_16x16x32_bf16(aql[rt][1], bh1, a, 0, 0, 0);
                a = __builtin_amdgcn_mfma_f32_16x16x32_bf16(aqh[rt][0], bl0, a, 0, 0, 0);
                a = __builtin_amdgcn_mfma_f32_16x16x32_bf16(aqh[rt][1], bl1, a, 0, 0, 0);
                s[rt][tc] = a;
            }
        }

        // online softmax; row (rt, quad*4+r) lives across the quad's 16 lanes
        #pragma unroll
        for (int rt = 0; rt < 2; ++rt)
            #pragma unroll
            for (int r = 0; r < 4; ++r) {
                float lm = fmaxf(fmaxf(s[rt][0][r], s[rt][1][r]),
                                 fmaxf(s[rt][2][r], s[rt][3][r]));
                #pragma unroll
                for (int off = 1; off < 16; off <<= 1)
                    lm = fmaxf(lm, __shfl_xor(lm, off, 16));
                const float mnew = fmaxf(m_run[rt][r], lm);
                const float alpha = __expf(m_run[rt][r] - mnew);
                m_run[rt][r] = mnew;
                float ls = 0.f;
                #pragma unroll
                for (int tc = 0; tc < 4; ++tc) {
                    const float pv = __expf(s[rt][tc][r] - mnew);
                    s[rt][tc][r] = pv;
                    ls += pv;
                }
                #pragma unroll
                for (int off = 1; off < 16; off <<= 1)
                    ls += __shfl_xor(ls, off, 16);
                l_run[rt][r] = l_run[rt][r] * alpha + ls;
                o[rt][0][r] *= alpha; o[rt][1][r] *= alpha;
                o[rt][2][r] *= alpha; o[rt][3][r] *= alpha;
            }

        // P: C-layout -> wave-private LDS -> A-layout (in-wave ordering only)
        #pragma unroll
        for (int rt = 0; rt < 2; ++rt)
            #pragma unroll
            for (int tc = 0; tc < 4; ++tc)
                #pragma unroll
                for (int r = 0; r < 4; ++r)
                    pbuf[w][(rt*16 + quad*4 + r)*72 + tc*16 + l15] = f2bf(s[rt][tc][r]);

        // O += P @ V
        bf16x8 bv0[4], bv1[4];
        #pragma unroll
        for (int tc = 0; tc < 4; ++tc) {
            const int a0 = (tc*16 + l15)*64 + ((quad       ^ (l15 & 7)) * 8);
            const int a1 = (tc*16 + l15)*64 + (((quad + 4) ^ (l15 & 7)) * 8);
            bv0[tc] = *(const bf16x8*)(vs + a0);
            bv1[tc] = *(const bf16x8*)(vs + a1);
        }
        #pragma unroll
        for (int rt = 0; rt < 2; ++rt) {
            const bf16x8 ap0 = *(const bf16x8*)&pbuf[w][(rt*16 + l15)*72 + quad*8];
            const bf16x8 ap1 = *(const bf16x8*)&pbuf[w][(rt*16 + l15)*72 + 32 + quad*8];
            #pragma unroll
            for (int tc = 0; tc < 4; ++tc) {
                o[rt][tc] = __builtin_amdgcn_mfma_f32_16x16x32_bf16(ap0, bv0[tc], o[rt][tc], 0, 0, 0);
                o[rt][tc] = __builtin_amdgcn_mfma_f32_16x16x32_bf16(ap1, bv1[tc], o[rt][tc], 0, 0, 0);
            }
        }
    }

    // epilogue: ctx = O/l + mask@V, split hi/lo bf16
    const float* mvp = mv + ((size_t)p * NH + h) * HSZ;
    #pragma unroll
    for (int rt = 0; rt < 2; ++rt)
        #pragma unroll
        for (int r = 0; r < 4; ++r) {
            const float inv = 1.0f / l_run[rt][r];
            const int row = qt*128 + w*32 + rt*16 + quad*4 + r;
            const size_t base = ((size_t)p * NS + row) * DM + h * 64;
            #pragma unroll
            for (int tc = 0; tc < 4; ++tc) {
                const float v = o[rt][tc][r] * inv + mvp[tc*16 + l15];
                const ushort hi = f2bf(v);
                ctxh[base + tc*16 + l15] = hi;
                ctxl[base + tc*16 + l15] = f2bf(v - bf2f(hi));
            }
        }
}

extern "C" void kernel_launch(void* const* d_in, const int* in_sizes, int n_in,
                              void* d_out, int out_size, void* d_ws, size_t ws_size,
                              hipStream_t stream)
{
    const float* x      = (const float*)d_in[0];
    const float* mask   = (const float*)d_in[1];
    const float* qkv_w  = (const float*)d_in[2];
    const float* qkv_b  = (const float*)d_in[3];
    const float* proj_w = (const float*)d_in[4];
    const float* proj_b = (const float*)d_in[5];
    float* out = (float*)d_out;

    // workspace (~97.5 MB): x hi/lo dead after qkv GEMM -> ctx aliases it.
    const size_t HE = (size_t)PB * NH * NS * HSZ;   // 6291456
    const size_t QW = (size_t)DM * 3 * DM;          // 1769472
    const size_t PW = (size_t)DM * DM;              // 589824
    ushort* xh  = (ushort*)d_ws;
    ushort* xl  = xh + HE;
    ushort* qwh = xl + HE;
    ushort* qwl = qwh + QW;
    ushort* pwh = qwl + QW;
    ushort* pwl = pwh + PW;
    ushort* qhv = pwl + PW;
    ushort* qlv = qhv + HE;
    ushort* khv = qlv + HE;
    ushort* klv = khv + HE;
    ushort* vtv = klv + HE;
    float*  mvb = (float*)(vtv + HE);
    ushort* cth = xh;   // alias
    ushort* ctl = xl;

    split_kernel<<<2048, 256, 0, stream>>>(x, xh, xl, (int)(HE / 4));
    splitT_kernel<<<dim3(3*DM/32, DM/32), dim3(32, 8), 0, stream>>>(qkv_w, qwh, qwl, DM, 3*DM);
    splitT_kernel<<<dim3(DM/32,   DM/32), dim3(32, 8), 0, stream>>>(proj_w, pwh, pwl, DM, DM);

    gemm_bf16s<1><<<dim3(3*DM/128, PB*NS/128), 256, 0, stream>>>(
        xh, xl, qwh, qwl, qkv_b, nullptr, qhv, qlv, khv, klv, vtv, DM);

    mv_kernel<<<dim3(PB*NH), 256, 0, stream>>>(mask, vtv, mvb);

    attn_mfma_kernel<<<dim3(NS/128, NH, PB), 256, 0, stream>>>(
        qhv, qlv, khv, klv, vtv, mvb, cth, ctl);

    gemm_bf16s<0><<<dim3(DM/128, PB*NS/128), 256, 0, stream>>>(
        cth, ctl, pwh, pwl, proj_b, out, nullptr, nullptr, nullptr, nullptr, nullptr, DM);
}

// Round 5
// 293.134 us; speedup vs baseline: 3.2650x; 1.1779x over previous
//
#include <hip/hip_runtime.h>
#include <hip/hip_bf16.h>
#include <cstdint>
#include <math.h>

constexpr int PB = 8;
constexpr int NS = 1024;
constexpr int DM = 768;
constexpr int NH = 12;
constexpr int HSZ = 64;
// reference MULTIPLIES scores by sqrt(head_size)=8; folded into q at qkv epilogue.
constexpr float EOFF = 88.0f;   // fixed softmax offset: p = exp(s-EOFF)/sum

typedef short bf16x8 __attribute__((ext_vector_type(8)));
typedef float floatx4 __attribute__((ext_vector_type(4)));

__device__ __forceinline__ ushort f2bf(float x) {
    __hip_bfloat16 b = __float2bfloat16(x);
    return *reinterpret_cast<ushort*>(&b);
}
__device__ __forceinline__ float bf2f(ushort u) {
    __hip_bfloat16 b = *reinterpret_cast<__hip_bfloat16*>(&u);
    return __bfloat162float(b);
}

#define GLDS(g, l)                                                             \
    __builtin_amdgcn_global_load_lds(                                          \
        (const __attribute__((address_space(1))) void*)(g),                    \
        (__attribute__((address_space(3))) void*)(l), 16, 0, 0)

// ---------------- split fp32 -> (hi, lo) bf16, elementwise ----------------
__global__ void split_kernel(const float* __restrict__ x, ushort* __restrict__ hi,
                             ushort* __restrict__ lo, int n4)
{
    int i = blockIdx.x * blockDim.x + threadIdx.x;
    const int stride = gridDim.x * blockDim.x;
    for (; i < n4; i += stride) {
        const float4 v = ((const float4*)x)[i];
        ushort4 h, l;
        h.x = f2bf(v.x); l.x = f2bf(v.x - bf2f(h.x));
        h.y = f2bf(v.y); l.y = f2bf(v.y - bf2f(h.y));
        h.z = f2bf(v.z); l.z = f2bf(v.z - bf2f(h.z));
        h.w = f2bf(v.w); l.w = f2bf(v.w - bf2f(h.w));
        ((ushort4*)hi)[i] = h;
        ((ushort4*)lo)[i] = l;
    }
}

// ------------- split + transpose: w (K x N) -> wT hi/lo (N x K) -------------
__global__ void splitT_kernel(const float* __restrict__ w, ushort* __restrict__ hiT,
                              ushort* __restrict__ loT, int K, int N)
{
    __shared__ float tile[32][33];
    const int tx = threadIdx.x, ty = threadIdx.y;   // (32, 8)
    const int bx = blockIdx.x, by = blockIdx.y;     // N/32, K/32
    #pragma unroll
    for (int r = 0; r < 4; ++r)
        tile[ty + r*8][tx] = w[(size_t)(by*32 + ty + r*8) * N + bx*32 + tx];
    __syncthreads();
    #pragma unroll
    for (int r = 0; r < 4; ++r) {
        const int n = bx*32 + ty + r*8;
        const int k = by*32 + tx;
        const float v = tile[tx][ty + r*8];
        const ushort h = f2bf(v);
        hiT[(size_t)n * K + k] = h;
        loT[(size_t)n * K + k] = f2bf(v - bf2f(h));
    }
}

// ---------------- split-bf16 MFMA GEMM ----------------
// C = A(MxK) @ B(KxN); A hi/lo bf16 row-major, B TRANSPOSED hi/lo (NxK).
// 128x128 tile, BK=32, 4 waves, 4x4 MFMA tiles each.
// SPLIT=1: 3-pass (hh+hl+lh); V-column blocks (MODE1, blockIdx.x>=12) and
// SPLIT=0 run single-pass hi*hi.
// MODE 0: fp32 store. MODE 1: qkv scatter (q scaled by 8) + vT.
template <int MODE, int SPLIT>
__global__ __launch_bounds__(256, 2)
void gemm_bf16s(const ushort* __restrict__ Ah, const ushort* __restrict__ Al,
                const ushort* __restrict__ Bh, const ushort* __restrict__ Bl,
                const float* __restrict__ bias, float* __restrict__ outf,
                ushort* __restrict__ qh, ushort* __restrict__ ql,
                ushort* __restrict__ kh, ushort* __restrict__ kl,
                ushort* __restrict__ vt, int K)
{
    __shared__ __align__(16) ushort Ah_s[128*32];
    __shared__ __align__(16) ushort Bh_s[128*32];
    __shared__ __align__(16) ushort Al_s[SPLIT ? 128*32 : 8];
    __shared__ __align__(16) ushort Bl_s[SPLIT ? 128*32 : 8];

    const int t    = threadIdx.x;
    const int w    = t >> 6;
    const int lane = t & 63;
    const int l15  = lane & 15;
    const int quad = lane >> 4;
    const int wm = w >> 1, wn = w & 1;
    const int m0 = blockIdx.y * 128, n0 = blockIdx.x * 128;

    // V-columns need only bf16 accuracy -> single pass (block-uniform branch)
    const bool dosplit = SPLIT && !(MODE == 1 && blockIdx.x >= 12);

    floatx4 acc[4][4];
    #pragma unroll
    for (int i = 0; i < 4; ++i)
        #pragma unroll
        for (int j = 0; j < 4; ++j) acc[i][j] = floatx4{0.f, 0.f, 0.f, 0.f};

    const int srow = lane >> 2;
    const int sseg = (lane & 3) ^ (srow & 3);
    const int r0   = w * 32;
    const size_t aBase = (size_t)(m0 + r0 + srow) * K + sseg * 8;
    const size_t bBase = (size_t)(n0 + r0 + srow) * K + sseg * 8;
    const int ldsBase = r0 * 32;
    const int fsl = (quad ^ (l15 & 3)) * 8;

    for (int k0 = 0; k0 < K; k0 += 32) {
        #pragma unroll
        for (int j = 0; j < 2; ++j) {
            const size_t ga = aBase + (size_t)j * 16 * K + k0;
            const size_t gb = bBase + (size_t)j * 16 * K + k0;
            const int lb = ldsBase + j * 512;
            GLDS(Ah + ga, Ah_s + lb);
            GLDS(Bh + gb, Bh_s + lb);
            if (dosplit) {
                GLDS(Al + ga, Al_s + lb);
                GLDS(Bl + gb, Bl_s + lb);
            }
        }
        __syncthreads();

        bf16x8 fah[4], fbh[4];
        #pragma unroll
        for (int i = 0; i < 4; ++i) {
            fah[i] = *(const bf16x8*)(Ah_s + (wm*64 + i*16 + l15) * 32 + fsl);
            fbh[i] = *(const bf16x8*)(Bh_s + (wn*64 + i*16 + l15) * 32 + fsl);
        }
        if (dosplit) {
            bf16x8 fal[4], fbl[4];
            #pragma unroll
            for (int i = 0; i < 4; ++i) {
                fal[i] = *(const bf16x8*)(Al_s + (wm*64 + i*16 + l15) * 32 + fsl);
                fbl[i] = *(const bf16x8*)(Bl_s + (wn*64 + i*16 + l15) * 32 + fsl);
            }
            #pragma unroll
            for (int mt = 0; mt < 4; ++mt)
                #pragma unroll
                for (int nt = 0; nt < 4; ++nt) {
                    acc[mt][nt] = __builtin_amdgcn_mfma_f32_16x16x32_bf16(fah[mt], fbh[nt], acc[mt][nt], 0, 0, 0);
                    acc[mt][nt] = __builtin_amdgcn_mfma_f32_16x16x32_bf16(fah[mt], fbl[nt], acc[mt][nt], 0, 0, 0);
                    acc[mt][nt] = __builtin_amdgcn_mfma_f32_16x16x32_bf16(fal[mt], fbh[nt], acc[mt][nt], 0, 0, 0);
                }
        } else {
            #pragma unroll
            for (int mt = 0; mt < 4; ++mt)
                #pragma unroll
                for (int nt = 0; nt < 4; ++nt)
                    acc[mt][nt] = __builtin_amdgcn_mfma_f32_16x16x32_bf16(fah[mt], fbh[nt], acc[mt][nt], 0, 0, 0);
        }
        __syncthreads();
    }

    if (MODE == 0) {
        #pragma unroll
        for (int nt = 0; nt < 4; ++nt) {
            const int col = n0 + wn*64 + nt*16 + l15;
            const float bval = bias[col];
            #pragma unroll
            for (int mt = 0; mt < 4; ++mt) {
                const int row0 = m0 + wm*64 + mt*16 + quad*4;
                #pragma unroll
                for (int r = 0; r < 4; ++r)
                    outf[(size_t)(row0 + r) * DM + col] = acc[mt][nt][r] + bval;
            }
        }
    } else {
        const int jbase = n0 + wn*64;
        const int c  = jbase / DM;
        const int hh = (jbase % DM) >> 6;
        const int pp = (m0 + wm*64) >> 10;
        const size_t head = (size_t)pp * NH + hh;
        #pragma unroll
        for (int nt = 0; nt < 4; ++nt) {
            const int s = nt*16 + l15;
            const float bval = bias[jbase + s];
            #pragma unroll
            for (int mt = 0; mt < 4; ++mt) {
                const int tok0 = m0 + wm*64 + mt*16 + quad*4;
                const int nn0  = tok0 & 1023;
                if (c == 2) {
                    ushort4 pk;
                    pk.x = f2bf(acc[mt][nt][0] + bval);
                    pk.y = f2bf(acc[mt][nt][1] + bval);
                    pk.z = f2bf(acc[mt][nt][2] + bval);
                    pk.w = f2bf(acc[mt][nt][3] + bval);
                    *(ushort4*)(vt + (head*HSZ + s) * NS + nn0) = pk;
                } else {
                    ushort* dh = (c == 0 ? qh : kh);
                    ushort* dl = (c == 0 ? ql : kl);
                    const float qscale = (c == 0) ? 8.0f : 1.0f;   // fold scale into q (exact)
                    #pragma unroll
                    for (int r = 0; r < 4; ++r) {
                        const float v = (acc[mt][nt][r] + bval) * qscale;
                        const ushort hi = f2bf(v);
                        dh[(head*NS + nn0 + r) * HSZ + s] = hi;
                        dl[(head*NS + nn0 + r) * HSZ + s] = f2bf(v - bf2f(hi));
                    }
                }
            }
        }
    }
}

// ---------------- mask @ V per (p,h): mv[p][h][c] ----------------
__global__ void mv_kernel(const float* __restrict__ mask, const ushort* __restrict__ vt,
                          float* __restrict__ mv)
{
    __shared__ float red[4][64];
    const int ph = blockIdx.x;
    const int t  = threadIdx.x;
    const int c  = t & 63, part = t >> 6;
    const ushort* vrow = vt + ((size_t)ph * HSZ + c) * NS + part * 256;
    const float*  mrow = mask + (size_t)(ph / NH) * NS + part * 256;
    float acc = 0.f;
    for (int k = 0; k < 256; k += 4) {
        const ushort4 v4 = *(const ushort4*)(vrow + k);
        const float4  m4 = *(const float4*)(mrow + k);
        acc += m4.x * bf2f(v4.x) + m4.y * bf2f(v4.y)
             + m4.z * bf2f(v4.z) + m4.w * bf2f(v4.w);
    }
    red[part][c] = acc;
    __syncthreads();
    if (t < 64)
        mv[(size_t)ph * HSZ + t] = red[0][t] + red[1][t] + red[2][t] + red[3][t];
}

// ---------------- MFMA flash attention, transposed-S fixed-offset ----------------
// Block = 128 q-rows x (p,h); 4 waves, wave w owns rows [w*32, w*32+32).
// S^T = K·Q^T (operand swap: same Q register frags, same K LDS reads) so the
// C-layout puts each q-row in ONE lane (col=l15) -> softmax sums are per-lane.
// Fixed-offset softmax p~ = exp(s - 88): no running max, no alpha rescale; the
// row-sum l is reduced once in the epilogue (2 shfl). P~ rows are contiguous
// in keys -> ds_write_b64; PV as O^T = V^T·P^T (V LDS reads unchanged).
// ctx = O/l + mv (precomputed mask@V == exact post-softmax mask-add), bf16.
__global__ __launch_bounds__(256, 3)
void attn_mfma_kernel(const ushort* __restrict__ qh, const ushort* __restrict__ ql,
                      const ushort* __restrict__ kh, const ushort* __restrict__ kl,
                      const ushort* __restrict__ vt, const float* __restrict__ mv,
                      ushort* __restrict__ ctx)
{
    __shared__ __align__(16) ushort khs[64*64];
    __shared__ __align__(16) ushort kls[64*64];
    __shared__ __align__(16) ushort vs [64*64];
    __shared__ __align__(16) ushort pbuf[4][32][72];   // [wave][qrow][key], b128-aligned rows

    const int t    = threadIdx.x;
    const int w    = t >> 6;
    const int lane = t & 63;
    const int l15  = lane & 15;
    const int quad = lane >> 4;
    const int qt = blockIdx.x, h = blockIdx.y, p = blockIdx.z;
    const size_t headoff = ((size_t)p * NH + h) * (size_t)(NS * HSZ);

    // persistent Q frags (B-operand): row = qt*128 + w*32 + rt*16 + l15
    bf16x8 qfh[2][2], qfl[2][2];
    #pragma unroll
    for (int rt = 0; rt < 2; ++rt) {
        const size_t r = (size_t)(qt*128 + w*32 + rt*16 + l15);
        const ushort* bh = qh + headoff + r * HSZ + quad*8;
        const ushort* bl = ql + headoff + r * HSZ + quad*8;
        qfh[rt][0] = *(const bf16x8*)(bh);
        qfh[rt][1] = *(const bf16x8*)(bh + 32);
        qfl[rt][0] = *(const bf16x8*)(bl);
        qfl[rt][1] = *(const bf16x8*)(bl + 32);
    }

    floatx4 o[2][4];    // O^T acc: [rt][c-tile]; lane col = qrow, rows = c
    float lsum[2] = {0.f, 0.f};
    #pragma unroll
    for (int rt = 0; rt < 2; ++rt)
        #pragma unroll
        for (int tc = 0; tc < 4; ++tc) o[rt][tc] = floatx4{0.f, 0.f, 0.f, 0.f};

    const int srow8 = lane >> 3;
    const int sslot = lane & 7;

    for (int kt = 0; kt < 16; ++kt) {
        __syncthreads();   // previous tile's LDS reads complete
        #pragma unroll
        for (int j = 0; j < 2; ++j) {
            const int row = w*16 + j*8 + srow8;          // tile-local 0..63
            const int seg = sslot ^ (row & 7);           // XOR swizzle (global side)
            const size_t gk = headoff + (size_t)(kt*64 + row) * HSZ + seg*8;
            const size_t gv = headoff + (size_t)row * NS + kt*64 + seg*8;
            const int ldst = (w*16 + j*8) * 64;
            GLDS(kh + gk, khs + ldst);
            GLDS(kl + gk, kls + ldst);
            GLDS(vt + gv, vs  + ldst);
        }
        __syncthreads();   // staged data visible

        // S^T = K Q^T (split: kh*qh + kl*qh + kh*ql); exp + per-lane sum; P->LDS
        #pragma unroll
        for (int tk = 0; tk < 4; ++tk) {
            const int a0 = (tk*16 + l15)*64 + ((quad       ^ (l15 & 7)) * 8);
            const int a1 = (tk*16 + l15)*64 + (((quad + 4) ^ (l15 & 7)) * 8);
            const bf16x8 bh0 = *(const bf16x8*)(khs + a0);
            const bf16x8 bh1 = *(const bf16x8*)(khs + a1);
            const bf16x8 bl0 = *(const bf16x8*)(kls + a0);
            const bf16x8 bl1 = *(const bf16x8*)(kls + a1);
            #pragma unroll
            for (int rt = 0; rt < 2; ++rt) {
                floatx4 a = floatx4{0.f, 0.f, 0.f, 0.f};
                a = __builtin_amdgcn_mfma_f32_16x16x32_bf16(bh0, qfh[rt][0], a, 0, 0, 0);
                a = __builtin_amdgcn_mfma_f32_16x16x32_bf16(bh1, qfh[rt][1], a, 0, 0, 0);
                a = __builtin_amdgcn_mfma_f32_16x16x32_bf16(bl0, qfh[rt][0], a, 0, 0, 0);
                a = __builtin_amdgcn_mfma_f32_16x16x32_bf16(bl1, qfh[rt][1], a, 0, 0, 0);
                a = __builtin_amdgcn_mfma_f32_16x16x32_bf16(bh0, qfl[rt][0], a, 0, 0, 0);
                a = __builtin_amdgcn_mfma_f32_16x16x32_bf16(bh1, qfl[rt][1], a, 0, 0, 0);
                const float e0 = __expf(a[0] - EOFF);
                const float e1 = __expf(a[1] - EOFF);
                const float e2 = __expf(a[2] - EOFF);
                const float e3 = __expf(a[3] - EOFF);
                lsum[rt] += (e0 + e1) + (e2 + e3);
                ushort4 pk;
                pk.x = f2bf(e0); pk.y = f2bf(e1); pk.z = f2bf(e2); pk.w = f2bf(e3);
                *(ushort4*)&pbuf[w][rt*16 + l15][tk*16 + quad*4] = pk;
            }
        }

        // O^T += V^T P^T  (wave-private pbuf: in-wave LDS ordering suffices)
        #pragma unroll
        for (int rt = 0; rt < 2; ++rt) {
            const bf16x8 bp0 = *(const bf16x8*)&pbuf[w][rt*16 + l15][quad*8];
            const bf16x8 bp1 = *(const bf16x8*)&pbuf[w][rt*16 + l15][quad*8 + 32];
            #pragma unroll
            for (int tc = 0; tc < 4; ++tc) {
                const int v0 = (tc*16 + l15)*64 + ((quad       ^ (l15 & 7)) * 8);
                const int v1 = (tc*16 + l15)*64 + (((quad + 4) ^ (l15 & 7)) * 8);
                const bf16x8 va0 = *(const bf16x8*)(vs + v0);
                const bf16x8 va1 = *(const bf16x8*)(vs + v1);
                o[rt][tc] = __builtin_amdgcn_mfma_f32_16x16x32_bf16(va0, bp0, o[rt][tc], 0, 0, 0);
                o[rt][tc] = __builtin_amdgcn_mfma_f32_16x16x32_bf16(va1, bp1, o[rt][tc], 0, 0, 0);
            }
        }
    }

    // epilogue: reduce l across quads (lanes sharing l15), ctx = O/l + mask@V
    float inv[2];
    #pragma unroll
    for (int rt = 0; rt < 2; ++rt) {
        float l = lsum[rt];
        l += __shfl_xor(l, 16);
        l += __shfl_xor(l, 32);
        inv[rt] = 1.0f / l;
    }
    const float* mvp = mv + ((size_t)p * NH + h) * HSZ;
    #pragma unroll
    for (int rt = 0; rt < 2; ++rt) {
        const int row = qt*128 + w*32 + rt*16 + l15;
        const size_t base = ((size_t)p * NS + row) * DM + h * 64;
        #pragma unroll
        for (int tc = 0; tc < 4; ++tc) {
            const int c0 = tc*16 + quad*4;
            ushort4 pk;
            pk.x = f2bf(o[rt][tc][0] * inv[rt] + mvp[c0 + 0]);
            pk.y = f2bf(o[rt][tc][1] * inv[rt] + mvp[c0 + 1]);
            pk.z = f2bf(o[rt][tc][2] * inv[rt] + mvp[c0 + 2]);
            pk.w = f2bf(o[rt][tc][3] * inv[rt] + mvp[c0 + 3]);
            *(ushort4*)(ctx + base + c0) = pk;
        }
    }
}

extern "C" void kernel_launch(void* const* d_in, const int* in_sizes, int n_in,
                              void* d_out, int out_size, void* d_ws, size_t ws_size,
                              hipStream_t stream)
{
    const float* x      = (const float*)d_in[0];
    const float* mask   = (const float*)d_in[1];
    const float* qkv_w  = (const float*)d_in[2];
    const float* qkv_b  = (const float*)d_in[3];
    const float* proj_w = (const float*)d_in[4];
    const float* proj_b = (const float*)d_in[5];
    float* out = (float*)d_out;

    // workspace (~97.5 MB): x hi/lo dead after qkv GEMM -> ctx (bf16) aliases xh.
    const size_t HE = (size_t)PB * NH * NS * HSZ;   // 6291456
    const size_t QW = (size_t)DM * 3 * DM;          // 1769472
    const size_t PW = (size_t)DM * DM;              // 589824
    ushort* xh  = (ushort*)d_ws;
    ushort* xl  = xh + HE;
    ushort* qwh = xl + HE;
    ushort* qwl = qwh + QW;
    ushort* pwh = qwl + QW;
    ushort* pwl = pwh + PW;
    ushort* qhv = pwl + PW;
    ushort* qlv = qhv + HE;
    ushort* khv = qlv + HE;
    ushort* klv = khv + HE;
    ushort* vtv = klv + HE;
    float*  mvb = (float*)(vtv + HE);
    ushort* cth = xh;   // alias: ctx bf16 over dead x_hi

    split_kernel<<<2048, 256, 0, stream>>>(x, xh, xl, (int)(HE / 4));
    splitT_kernel<<<dim3(3*DM/32, DM/32), dim3(32, 8), 0, stream>>>(qkv_w, qwh, qwl, DM, 3*DM);
    splitT_kernel<<<dim3(DM/32,   DM/32), dim3(32, 8), 0, stream>>>(proj_w, pwh, pwl, DM, DM);

    gemm_bf16s<1, 1><<<dim3(3*DM/128, PB*NS/128), 256, 0, stream>>>(
        xh, xl, qwh, qwl, qkv_b, nullptr, qhv, qlv, khv, klv, vtv, DM);

    mv_kernel<<<dim3(PB*NH), 256, 0, stream>>>(mask, vtv, mvb);

    attn_mfma_kernel<<<dim3(NS/128, NH, PB), 256, 0, stream>>>(
        qhv, qlv, khv, klv, vtv, mvb, cth);

    gemm_bf16s<0, 0><<<dim3(DM/128, PB*NS/128), 256, 0, stream>>>(
        cth, nullptr, pwh, nullptr, proj_b, out, nullptr, nullptr, nullptr, nullptr,
        nullptr, DM);
}

// Round 6
// 266.847 us; speedup vs baseline: 3.5866x; 1.0985x over previous
//
#include <hip/hip_runtime.h>
#include <hip/hip_bf16.h>
#include <cstdint>
#include <math.h>

constexpr int PB = 8;
constexpr int NS = 1024;
constexpr int DM = 768;
constexpr int NH = 12;
constexpr int HSZ = 64;
// reference MULTIPLIES scores by sqrt(head_size)=8; folded into q at qkv epilogue.
constexpr float EOFF = 88.0f;   // fixed softmax offset: p = exp(s-EOFF)/sum

typedef short bf16x8 __attribute__((ext_vector_type(8)));
typedef float floatx4 __attribute__((ext_vector_type(4)));

__device__ __forceinline__ ushort f2bf(float x) {
    __hip_bfloat16 b = __float2bfloat16(x);
    return *reinterpret_cast<ushort*>(&b);
}
__device__ __forceinline__ float bf2f(ushort u) {
    __hip_bfloat16 b = *reinterpret_cast<__hip_bfloat16*>(&u);
    return __bfloat162float(b);
}

#define GLDS(g, l)                                                             \
    __builtin_amdgcn_global_load_lds(                                          \
        (const __attribute__((address_space(1))) void*)(g),                    \
        (__attribute__((address_space(3))) void*)(l), 16, 0, 0)

// ---------------- split fp32 -> (hi, lo) bf16, elementwise ----------------
__global__ void split_kernel(const float* __restrict__ x, ushort* __restrict__ hi,
                             ushort* __restrict__ lo, int n4)
{
    int i = blockIdx.x * blockDim.x + threadIdx.x;
    const int stride = gridDim.x * blockDim.x;
    for (; i < n4; i += stride) {
        const float4 v = ((const float4*)x)[i];
        ushort4 h, l;
        h.x = f2bf(v.x); l.x = f2bf(v.x - bf2f(h.x));
        h.y = f2bf(v.y); l.y = f2bf(v.y - bf2f(h.y));
        h.z = f2bf(v.z); l.z = f2bf(v.z - bf2f(h.z));
        h.w = f2bf(v.w); l.w = f2bf(v.w - bf2f(h.w));
        ((ushort4*)hi)[i] = h;
        ((ushort4*)lo)[i] = l;
    }
}

// ------------- split + transpose: w (K x N) -> wT hi/lo (N x K) -------------
__global__ void splitT_kernel(const float* __restrict__ w, ushort* __restrict__ hiT,
                              ushort* __restrict__ loT, int K, int N)
{
    __shared__ float tile[32][33];
    const int tx = threadIdx.x, ty = threadIdx.y;   // (32, 8)
    const int bx = blockIdx.x, by = blockIdx.y;     // N/32, K/32
    #pragma unroll
    for (int r = 0; r < 4; ++r)
        tile[ty + r*8][tx] = w[(size_t)(by*32 + ty + r*8) * N + bx*32 + tx];
    __syncthreads();
    #pragma unroll
    for (int r = 0; r < 4; ++r) {
        const int n = bx*32 + ty + r*8;
        const int k = by*32 + tx;
        const float v = tile[tx][ty + r*8];
        const ushort h = f2bf(v);
        hiT[(size_t)n * K + k] = h;
        loT[(size_t)n * K + k] = f2bf(v - bf2f(h));
    }
}

// ---------------- 3-pass split-bf16 MFMA GEMM, q/k columns only ----------------
// C = A(MxK) @ B(KxN), N = 1536 (q then k heads). A hi/lo row-major, B
// transposed hi/lo (NxK). 128x128 tile, BK=32, 4 waves, 4x4 MFMA tiles.
// Epilogue: scatter q (scaled by 8) / k as split hi/lo bf16 (P,H,N,64).
__global__ __launch_bounds__(256, 2)
void gemm_qk(const ushort* __restrict__ Ah, const ushort* __restrict__ Al,
             const ushort* __restrict__ Bh, const ushort* __restrict__ Bl,
             const float* __restrict__ bias,
             ushort* __restrict__ qh, ushort* __restrict__ ql,
             ushort* __restrict__ kh, ushort* __restrict__ kl, int K)
{
    __shared__ __align__(16) ushort Ah_s[128*32];
    __shared__ __align__(16) ushort Al_s[128*32];
    __shared__ __align__(16) ushort Bh_s[128*32];
    __shared__ __align__(16) ushort Bl_s[128*32];

    const int t    = threadIdx.x;
    const int w    = t >> 6;
    const int lane = t & 63;
    const int l15  = lane & 15;
    const int quad = lane >> 4;
    const int wm = w >> 1, wn = w & 1;
    const int m0 = blockIdx.y * 128, n0 = blockIdx.x * 128;

    floatx4 acc[4][4];
    #pragma unroll
    for (int i = 0; i < 4; ++i)
        #pragma unroll
        for (int j = 0; j < 4; ++j) acc[i][j] = floatx4{0.f, 0.f, 0.f, 0.f};

    const int srow = lane >> 2;
    const int sseg = (lane & 3) ^ (srow & 3);
    const int r0   = w * 32;
    const size_t aBase = (size_t)(m0 + r0 + srow) * K + sseg * 8;
    const size_t bBase = (size_t)(n0 + r0 + srow) * K + sseg * 8;
    const int ldsBase = r0 * 32;
    const int fsl = (quad ^ (l15 & 3)) * 8;

    for (int k0 = 0; k0 < K; k0 += 32) {
        #pragma unroll
        for (int j = 0; j < 2; ++j) {
            const size_t ga = aBase + (size_t)j * 16 * K + k0;
            const size_t gb = bBase + (size_t)j * 16 * K + k0;
            const int lb = ldsBase + j * 512;
            GLDS(Ah + ga, Ah_s + lb);
            GLDS(Al + ga, Al_s + lb);
            GLDS(Bh + gb, Bh_s + lb);
            GLDS(Bl + gb, Bl_s + lb);
        }
        __syncthreads();

        bf16x8 fah[4], fal[4], fbh[4], fbl[4];
        #pragma unroll
        for (int i = 0; i < 4; ++i) {
            const int ra = (wm*64 + i*16 + l15) * 32 + fsl;
            fah[i] = *(const bf16x8*)(Ah_s + ra);
            fal[i] = *(const bf16x8*)(Al_s + ra);
            const int rb = (wn*64 + i*16 + l15) * 32 + fsl;
            fbh[i] = *(const bf16x8*)(Bh_s + rb);
            fbl[i] = *(const bf16x8*)(Bl_s + rb);
        }
        #pragma unroll
        for (int mt = 0; mt < 4; ++mt)
            #pragma unroll
            for (int nt = 0; nt < 4; ++nt) {
                acc[mt][nt] = __builtin_amdgcn_mfma_f32_16x16x32_bf16(fah[mt], fbh[nt], acc[mt][nt], 0, 0, 0);
                acc[mt][nt] = __builtin_amdgcn_mfma_f32_16x16x32_bf16(fah[mt], fbl[nt], acc[mt][nt], 0, 0, 0);
                acc[mt][nt] = __builtin_amdgcn_mfma_f32_16x16x32_bf16(fal[mt], fbh[nt], acc[mt][nt], 0, 0, 0);
            }
        __syncthreads();
    }

    // scatter: cols j = c*768 + h*64 + s, c in {0,1}; wave's 64-col span = one (c,h)
    const int jbase = n0 + wn*64;
    const int c  = jbase / DM;
    const int hh = (jbase % DM) >> 6;
    const int pp = (m0 + wm*64) >> 10;
    const size_t head = (size_t)pp * NH + hh;
    ushort* dh = (c == 0 ? qh : kh);
    ushort* dl = (c == 0 ? ql : kl);
    const float qscale = (c == 0) ? 8.0f : 1.0f;   // fold score scale into q (exact)
    #pragma unroll
    for (int nt = 0; nt < 4; ++nt) {
        const int s = nt*16 + l15;
        const float bval = bias[jbase + s];
        #pragma unroll
        for (int mt = 0; mt < 4; ++mt) {
            const int tok0 = m0 + wm*64 + mt*16 + quad*4;
            const int nn0  = tok0 & 1023;
            #pragma unroll
            for (int r = 0; r < 4; ++r) {
                const float v = (acc[mt][nt][r] + bval) * qscale;
                const ushort hi = f2bf(v);
                dh[(head*NS + nn0 + r) * HSZ + s] = hi;
                dl[(head*NS + nn0 + r) * HSZ + s] = f2bf(v - bf2f(hi));
            }
        }
    }
}

// ---------------- single-pass bf16 MFMA GEMM, BK=64 ----------------
// C = A(MxK)@B(KxN) hi-only. 128x128 tile, BK=64 (32 MFMA/barrier), 4 waves.
// MODE 0: fp32 store out[M][DM] + bias. MODE 2: vT scatter (P,H,64,N) + bias.
template <int MODE>
__global__ __launch_bounds__(256, 3)
void gemm_1p(const ushort* __restrict__ Ah, const ushort* __restrict__ Bh,
             const float* __restrict__ bias, float* __restrict__ outf,
             ushort* __restrict__ vt, int K)
{
    __shared__ __align__(16) ushort As[128*64];
    __shared__ __align__(16) ushort Bs[128*64];

    const int t    = threadIdx.x;
    const int w    = t >> 6;
    const int lane = t & 63;
    const int l15  = lane & 15;
    const int quad = lane >> 4;
    const int wm = w >> 1, wn = w & 1;
    const int m0 = blockIdx.y * 128, n0 = blockIdx.x * 128;

    floatx4 acc[4][4];
    #pragma unroll
    for (int i = 0; i < 4; ++i)
        #pragma unroll
        for (int j = 0; j < 4; ++j) acc[i][j] = floatx4{0.f, 0.f, 0.f, 0.f};

    const int srow8 = lane >> 3;   // 0..7
    const int sslot = lane & 7;

    for (int k0 = 0; k0 < K; k0 += 64) {
        #pragma unroll
        for (int j = 0; j < 4; ++j) {
            const int row = w*32 + j*8 + srow8;          // 0..127
            const int seg = sslot ^ (row & 7);           // XOR swizzle (global side)
            const int ldst = (w*32 + j*8) * 64;          // wave-uniform LDS base
            GLDS(Ah + (size_t)(m0 + row) * K + k0 + seg*8, As + ldst);
            GLDS(Bh + (size_t)(n0 + row) * K + k0 + seg*8, Bs + ldst);
        }
        __syncthreads();

        #pragma unroll
        for (int h2 = 0; h2 < 2; ++h2) {
            bf16x8 fa[4], fb[4];
            #pragma unroll
            for (int i = 0; i < 4; ++i) {
                const int sl = ((h2*4 + quad) ^ (l15 & 7)) * 8;
                fa[i] = *(const bf16x8*)(As + (wm*64 + i*16 + l15) * 64 + sl);
                fb[i] = *(const bf16x8*)(Bs + (wn*64 + i*16 + l15) * 64 + sl);
            }
            #pragma unroll
            for (int mt = 0; mt < 4; ++mt)
                #pragma unroll
                for (int nt = 0; nt < 4; ++nt)
                    acc[mt][nt] = __builtin_amdgcn_mfma_f32_16x16x32_bf16(fa[mt], fb[nt], acc[mt][nt], 0, 0, 0);
        }
        __syncthreads();
    }

    if (MODE == 0) {
        #pragma unroll
        for (int nt = 0; nt < 4; ++nt) {
            const int col = n0 + wn*64 + nt*16 + l15;
            const float bval = bias[col];
            #pragma unroll
            for (int mt = 0; mt < 4; ++mt) {
                const int row0 = m0 + wm*64 + mt*16 + quad*4;
                #pragma unroll
                for (int r = 0; r < 4; ++r)
                    outf[(size_t)(row0 + r) * DM + col] = acc[mt][nt][r] + bval;
            }
        }
    } else {
        // v columns: global col = jbase (0..767) -> head hh, within-head s
        const int jbase = n0 + wn*64;
        const int hh = jbase >> 6;
        const int pp = (m0 + wm*64) >> 10;
        const size_t head = (size_t)pp * NH + hh;
        #pragma unroll
        for (int nt = 0; nt < 4; ++nt) {
            const int s = nt*16 + l15;
            const float bval = bias[jbase + s];
            #pragma unroll
            for (int mt = 0; mt < 4; ++mt) {
                const int tok0 = m0 + wm*64 + mt*16 + quad*4;
                const int nn0  = tok0 & 1023;
                ushort4 pk;
                pk.x = f2bf(acc[mt][nt][0] + bval);
                pk.y = f2bf(acc[mt][nt][1] + bval);
                pk.z = f2bf(acc[mt][nt][2] + bval);
                pk.w = f2bf(acc[mt][nt][3] + bval);
                *(ushort4*)(vt + (head*HSZ + s) * NS + nn0) = pk;
            }
        }
    }
}

// ---------------- mask @ V per (p,h): mv[p][h][c] ----------------
__global__ void mv_kernel(const float* __restrict__ mask, const ushort* __restrict__ vt,
                          float* __restrict__ mv)
{
    __shared__ float red[4][64];
    const int ph = blockIdx.x;
    const int t  = threadIdx.x;
    const int c  = t & 63, part = t >> 6;
    const ushort* vrow = vt + ((size_t)ph * HSZ + c) * NS + part * 256;
    const float*  mrow = mask + (size_t)(ph / NH) * NS + part * 256;
    float acc = 0.f;
    for (int k = 0; k < 256; k += 4) {
        const ushort4 v4 = *(const ushort4*)(vrow + k);
        const float4  m4 = *(const float4*)(mrow + k);
        acc += m4.x * bf2f(v4.x) + m4.y * bf2f(v4.y)
             + m4.z * bf2f(v4.z) + m4.w * bf2f(v4.w);
    }
    red[part][c] = acc;
    __syncthreads();
    if (t < 64)
        mv[(size_t)ph * HSZ + t] = red[0][t] + red[1][t] + red[2][t] + red[3][t];
}

// ---------------- MFMA flash attention, transposed-S fixed-offset ----------------
// Block = 128 q-rows x (p,h); 4 waves, wave w owns rows [w*32, w*32+32).
// S^T = K·Q^T (operand swap) -> each q-row in ONE lane; fixed-offset softmax
// p~ = exp(s-88) (no running max/rescale); l reduced once in epilogue.
// PV as O^T = V^T·P^T. ctx = O/l + mv (exact post-softmax mask-add), bf16.
__global__ __launch_bounds__(256, 3)
void attn_mfma_kernel(const ushort* __restrict__ qh, const ushort* __restrict__ ql,
                      const ushort* __restrict__ kh, const ushort* __restrict__ kl,
                      const ushort* __restrict__ vt, const float* __restrict__ mv,
                      ushort* __restrict__ ctx)
{
    __shared__ __align__(16) ushort khs[64*64];
    __shared__ __align__(16) ushort kls[64*64];
    __shared__ __align__(16) ushort vs [64*64];
    __shared__ __align__(16) ushort pbuf[4][32][72];

    const int t    = threadIdx.x;
    const int w    = t >> 6;
    const int lane = t & 63;
    const int l15  = lane & 15;
    const int quad = lane >> 4;
    const int qt = blockIdx.x, h = blockIdx.y, p = blockIdx.z;
    const size_t headoff = ((size_t)p * NH + h) * (size_t)(NS * HSZ);

    bf16x8 qfh[2][2], qfl[2][2];
    #pragma unroll
    for (int rt = 0; rt < 2; ++rt) {
        const size_t r = (size_t)(qt*128 + w*32 + rt*16 + l15);
        const ushort* bh = qh + headoff + r * HSZ + quad*8;
        const ushort* bl = ql + headoff + r * HSZ + quad*8;
        qfh[rt][0] = *(const bf16x8*)(bh);
        qfh[rt][1] = *(const bf16x8*)(bh + 32);
        qfl[rt][0] = *(const bf16x8*)(bl);
        qfl[rt][1] = *(const bf16x8*)(bl + 32);
    }

    floatx4 o[2][4];
    float lsum[2] = {0.f, 0.f};
    #pragma unroll
    for (int rt = 0; rt < 2; ++rt)
        #pragma unroll
        for (int tc = 0; tc < 4; ++tc) o[rt][tc] = floatx4{0.f, 0.f, 0.f, 0.f};

    const int srow8 = lane >> 3;
    const int sslot = lane & 7;

    for (int kt = 0; kt < 16; ++kt) {
        __syncthreads();
        #pragma unroll
        for (int j = 0; j < 2; ++j) {
            const int row = w*16 + j*8 + srow8;
            const int seg = sslot ^ (row & 7);
            const size_t gk = headoff + (size_t)(kt*64 + row) * HSZ + seg*8;
            const size_t gv = headoff + (size_t)row * NS + kt*64 + seg*8;
            const int ldst = (w*16 + j*8) * 64;
            GLDS(kh + gk, khs + ldst);
            GLDS(kl + gk, kls + ldst);
            GLDS(vt + gv, vs  + ldst);
        }
        __syncthreads();

        #pragma unroll
        for (int tk = 0; tk < 4; ++tk) {
            const int a0 = (tk*16 + l15)*64 + ((quad       ^ (l15 & 7)) * 8);
            const int a1 = (tk*16 + l15)*64 + (((quad + 4) ^ (l15 & 7)) * 8);
            const bf16x8 bh0 = *(const bf16x8*)(khs + a0);
            const bf16x8 bh1 = *(const bf16x8*)(khs + a1);
            const bf16x8 bl0 = *(const bf16x8*)(kls + a0);
            const bf16x8 bl1 = *(const bf16x8*)(kls + a1);
            #pragma unroll
            for (int rt = 0; rt < 2; ++rt) {
                floatx4 a = floatx4{0.f, 0.f, 0.f, 0.f};
                a = __builtin_amdgcn_mfma_f32_16x16x32_bf16(bh0, qfh[rt][0], a, 0, 0, 0);
                a = __builtin_amdgcn_mfma_f32_16x16x32_bf16(bh1, qfh[rt][1], a, 0, 0, 0);
                a = __builtin_amdgcn_mfma_f32_16x16x32_bf16(bl0, qfh[rt][0], a, 0, 0, 0);
                a = __builtin_amdgcn_mfma_f32_16x16x32_bf16(bl1, qfh[rt][1], a, 0, 0, 0);
                a = __builtin_amdgcn_mfma_f32_16x16x32_bf16(bh0, qfl[rt][0], a, 0, 0, 0);
                a = __builtin_amdgcn_mfma_f32_16x16x32_bf16(bh1, qfl[rt][1], a, 0, 0, 0);
                const float e0 = __expf(a[0] - EOFF);
                const float e1 = __expf(a[1] - EOFF);
                const float e2 = __expf(a[2] - EOFF);
                const float e3 = __expf(a[3] - EOFF);
                lsum[rt] += (e0 + e1) + (e2 + e3);
                ushort4 pk;
                pk.x = f2bf(e0); pk.y = f2bf(e1); pk.z = f2bf(e2); pk.w = f2bf(e3);
                *(ushort4*)&pbuf[w][rt*16 + l15][tk*16 + quad*4] = pk;
            }
        }

        #pragma unroll
        for (int rt = 0; rt < 2; ++rt) {
            const bf16x8 bp0 = *(const bf16x8*)&pbuf[w][rt*16 + l15][quad*8];
            const bf16x8 bp1 = *(const bf16x8*)&pbuf[w][rt*16 + l15][quad*8 + 32];
            #pragma unroll
            for (int tc = 0; tc < 4; ++tc) {
                const int v0 = (tc*16 + l15)*64 + ((quad       ^ (l15 & 7)) * 8);
                const int v1 = (tc*16 + l15)*64 + (((quad + 4) ^ (l15 & 7)) * 8);
                const bf16x8 va0 = *(const bf16x8*)(vs + v0);
                const bf16x8 va1 = *(const bf16x8*)(vs + v1);
                o[rt][tc] = __builtin_amdgcn_mfma_f32_16x16x32_bf16(va0, bp0, o[rt][tc], 0, 0, 0);
                o[rt][tc] = __builtin_amdgcn_mfma_f32_16x16x32_bf16(va1, bp1, o[rt][tc], 0, 0, 0);
            }
        }
    }

    float inv[2];
    #pragma unroll
    for (int rt = 0; rt < 2; ++rt) {
        float l = lsum[rt];
        l += __shfl_xor(l, 16);
        l += __shfl_xor(l, 32);
        inv[rt] = 1.0f / l;
    }
    const float* mvp = mv + ((size_t)p * NH + h) * HSZ;
    #pragma unroll
    for (int rt = 0; rt < 2; ++rt) {
        const int row = qt*128 + w*32 + rt*16 + l15;
        const size_t base = ((size_t)p * NS + row) * DM + h * 64;
        #pragma unroll
        for (int tc = 0; tc < 4; ++tc) {
            const int c0 = tc*16 + quad*4;
            ushort4 pk;
            pk.x = f2bf(o[rt][tc][0] * inv[rt] + mvp[c0 + 0]);
            pk.y = f2bf(o[rt][tc][1] * inv[rt] + mvp[c0 + 1]);
            pk.z = f2bf(o[rt][tc][2] * inv[rt] + mvp[c0 + 2]);
            pk.w = f2bf(o[rt][tc][3] * inv[rt] + mvp[c0 + 3]);
            *(ushort4*)(ctx + base + c0) = pk;
        }
    }
}

extern "C" void kernel_launch(void* const* d_in, const int* in_sizes, int n_in,
                              void* d_out, int out_size, void* d_ws, size_t ws_size,
                              hipStream_t stream)
{
    const float* x      = (const float*)d_in[0];
    const float* mask   = (const float*)d_in[1];
    const float* qkv_w  = (const float*)d_in[2];
    const float* qkv_b  = (const float*)d_in[3];
    const float* proj_w = (const float*)d_in[4];
    const float* proj_b = (const float*)d_in[5];
    float* out = (float*)d_out;

    // workspace (~97.5 MB): x hi/lo dead after qkv GEMMs -> ctx (bf16) aliases xh.
    const size_t HE = (size_t)PB * NH * NS * HSZ;   // 6291456
    const size_t QW = (size_t)DM * 3 * DM;          // 1769472
    const size_t PW = (size_t)DM * DM;              // 589824
    ushort* xh  = (ushort*)d_ws;
    ushort* xl  = xh + HE;
    ushort* qwh = xl + HE;
    ushort* qwl = qwh + QW;
    ushort* pwh = qwl + QW;
    ushort* pwl = pwh + PW;
    ushort* qhv = pwl + PW;
    ushort* qlv = qhv + HE;
    ushort* khv = qlv + HE;
    ushort* klv = khv + HE;
    ushort* vtv = klv + HE;
    float*  mvb = (float*)(vtv + HE);
    ushort* cth = xh;   // alias: ctx bf16 over dead x_hi

    split_kernel<<<2048, 256, 0, stream>>>(x, xh, xl, (int)(HE / 4));
    splitT_kernel<<<dim3(3*DM/32, DM/32), dim3(32, 8), 0, stream>>>(qkv_w, qwh, qwl, DM, 3*DM);
    splitT_kernel<<<dim3(DM/32,   DM/32), dim3(32, 8), 0, stream>>>(proj_w, pwh, pwl, DM, DM);

    // q/k columns: 3-pass split GEMM (cols 0..1535)
    gemm_qk<<<dim3(12, PB*NS/128), 256, 0, stream>>>(
        xh, xl, qwh, qwl, qkv_b, qhv, qlv, khv, klv, DM);
    // v columns: single-pass BK=64 GEMM (cols 1536..2303 -> rows 1536.. of qwh)
    gemm_1p<2><<<dim3(DM/128, PB*NS/128), 256, 0, stream>>>(
        xh, qwh + (size_t)2*DM*DM, qkv_b + 2*DM, nullptr, vtv, DM);

    mv_kernel<<<dim3(PB*NH), 256, 0, stream>>>(mask, vtv, mvb);

    attn_mfma_kernel<<<dim3(NS/128, NH, PB), 256, 0, stream>>>(
        qhv, qlv, khv, klv, vtv, mvb, cth);

    gemm_1p<0><<<dim3(DM/128, PB*NS/128), 256, 0, stream>>>(
        cth, pwh, proj_b, out, nullptr, DM);
}